// Round 13
// baseline (457.925 us; speedup 1.0000x reference)
//
#include <hip/hip_runtime.h>
#include <hip/hip_bf16.h>

#define LRELU_ALPHA 0.2f

typedef __attribute__((ext_vector_type(8))) __bf16 bf16x8;
typedef __attribute__((ext_vector_type(4))) float f32x4;
typedef __attribute__((ext_vector_type(8))) unsigned short u16x8;
typedef __attribute__((ext_vector_type(4))) unsigned short u16x4;

__device__ __forceinline__ unsigned short f2bf(float f) {
  unsigned int u = __float_as_uint(f);
  u += 0x7fffu + ((u >> 16) & 1u);   // round-to-nearest-even
  return (unsigned short)(u >> 16);
}

// ---------------- fp32 tiled GEMM: wh1 = x @ W1 ----------------
__global__ __launch_bounds__(256) void gemm_f32_k(
    const float* __restrict__ A, const float* __restrict__ B,
    float* __restrict__ C, int M, int K, int Ncols)
{
  __shared__ float As[128][17];
  __shared__ float Bs[16][65];
  int t = threadIdx.x;
  int row0 = blockIdx.x * 128;
  int col0 = blockIdx.y * 64;
  int ty = t >> 4, tx = t & 15;
  float acc[8][4];
#pragma unroll
  for (int i = 0; i < 8; ++i)
#pragma unroll
    for (int j = 0; j < 4; ++j) acc[i][j] = 0.f;

  for (int kt = 0; kt < K; kt += 16) {
    __syncthreads();
    {
      int r = t >> 1, h = t & 1;
      const float4* src = (const float4*)(A + (size_t)(row0 + r) * K + kt + h * 8);
      float4 v0 = src[0], v1 = src[1];
      float* dst = &As[r][h * 8];
      dst[0]=v0.x; dst[1]=v0.y; dst[2]=v0.z; dst[3]=v0.w;
      dst[4]=v1.x; dst[5]=v1.y; dst[6]=v1.z; dst[7]=v1.w;
    }
    {
      int kr = t >> 4, seg = t & 15;
      const float4* src = (const float4*)(B + (size_t)(kt + kr) * Ncols + col0 + seg * 4);
      float4 v = src[0];
      float* dst = &Bs[kr][seg * 4];
      dst[0]=v.x; dst[1]=v.y; dst[2]=v.z; dst[3]=v.w;
    }
    __syncthreads();
#pragma unroll
    for (int k = 0; k < 16; ++k) {
      float bb[4];
#pragma unroll
      for (int j = 0; j < 4; ++j) bb[j] = Bs[k][tx * 4 + j];
#pragma unroll
      for (int i = 0; i < 8; ++i) {
        float aa = As[ty * 8 + i][k];
#pragma unroll
        for (int j = 0; j < 4; ++j) acc[i][j] = fmaf(aa, bb[j], acc[i][j]);
      }
    }
  }
#pragma unroll
  for (int i = 0; i < 8; ++i) {
    float4 v = make_float4(acc[i][0], acc[i][1], acc[i][2], acc[i][3]);
    *(float4*)(C + (size_t)(row0 + ty * 8 + i) * Ncols + col0 + tx * 4) = v;
  }
}

// ---------------- e1/e2 vectors: wave per row ----------------
__global__ __launch_bounds__(256) void calc_e_k(
    const float* __restrict__ Wh, const float* __restrict__ a,
    float* __restrict__ e1, float* __restrict__ e2, int F)
{
  int row = blockIdx.x * 4 + (threadIdx.x >> 6);
  int l = threadIdx.x & 63;
  const float* r = Wh + (size_t)row * F;
  float s1 = 0.f, s2 = 0.f;
  for (int f = l; f < F; f += 64) {
    float v = r[f];
    s1 += v * a[f];
    s2 += v * a[F + f];
  }
#pragma unroll
  for (int off = 32; off; off >>= 1) {
    s1 += __shfl_down(s1, off);
    s2 += __shfl_down(s2, off);
  }
  if (l == 0) { e1[row] = s1; e2[row] = s2; }
}

// ---------------- transpose + fp32->bf16: out[c][r] = bf16(in[r][c]) ----------------
__global__ void transpose_bf16_k(const float* __restrict__ in, unsigned short* __restrict__ out,
                                 int R, int Cc)
{
  __shared__ float tile[32][33];
  int tx = threadIdx.x, ty = threadIdx.y;
  int c0 = blockIdx.x * 32, r0 = blockIdx.y * 32;
  int c = c0 + tx;
  if (c < Cc) {
    for (int i = ty; i < 32; i += 8)
      tile[i][tx] = in[(size_t)(r0 + i) * Cc + c];
  }
  __syncthreads();
  int r = r0 + tx;
  for (int i = ty; i < 32; i += 8) {
    int cc = c0 + i;
    if (cc < Cc)
      out[(size_t)cc * R + r] = f2bf(tile[tx][i]);
  }
}

// ---------------- layer-1 masked softmax + inline adj bit-pack + bf16 dual write ----------------
__global__ __launch_bounds__(256) void att_softmax1_k(
    const int* __restrict__ adj, const float* __restrict__ e1,
    const float* __restrict__ e2, float* __restrict__ att,
    unsigned short* __restrict__ attb, unsigned* __restrict__ bits)
{
  __shared__ float red[4];
  int i = blockIdx.x, t = threadIdx.x;
  const int4* arow = (const int4*)(adj + (size_t)i * 8192);
  unsigned* brow = bits + (size_t)i * 256;
  float e1i = e1[i];
  float4 vv[8];
  float s = 0.f;
#pragma unroll
  for (int it = 0; it < 8; ++it) {
    int j4 = t + it * 256;               // int4/float4 index
    int4 a4 = arow[j4];
    float4 ev = *(const float4*)(e2 + j4 * 4);
    unsigned n = (unsigned)(a4.x > 0) | ((unsigned)(a4.y > 0) << 1)
               | ((unsigned)(a4.z > 0) << 2) | ((unsigned)(a4.w > 0) << 3);
    unsigned v = n << ((t & 7) * 4);
    v |= __shfl_xor(v, 1);
    v |= __shfl_xor(v, 2);
    v |= __shfl_xor(v, 4);
    if ((t & 7) == 0) brow[it * 32 + (t >> 3)] = v;
    float e, p0, p1, p2, p3;
    e = e1i + ev.x; e = e > 0.f ? e : LRELU_ALPHA * e; p0 = (a4.x > 0) ? __expf(e) : 0.f;
    e = e1i + ev.y; e = e > 0.f ? e : LRELU_ALPHA * e; p1 = (a4.y > 0) ? __expf(e) : 0.f;
    e = e1i + ev.z; e = e > 0.f ? e : LRELU_ALPHA * e; p2 = (a4.z > 0) ? __expf(e) : 0.f;
    e = e1i + ev.w; e = e > 0.f ? e : LRELU_ALPHA * e; p3 = (a4.w > 0) ? __expf(e) : 0.f;
    vv[it] = make_float4(p0, p1, p2, p3);
    s += (p0 + p1) + (p2 + p3);
  }
#pragma unroll
  for (int off = 32; off; off >>= 1) s += __shfl_xor(s, off);
  if ((t & 63) == 0) red[t >> 6] = s;
  __syncthreads();
  s = red[0] + red[1] + red[2] + red[3];
  float inv = 1.f / s;
  float4* orow = (float4*)(att + (size_t)i * 8192);
  unsigned short* obrow = attb + (size_t)i * 8192;
#pragma unroll
  for (int it = 0; it < 8; ++it) {
    int j4 = t + it * 256;
    float4 p = vv[it];
    p.x *= inv; p.y *= inv; p.z *= inv; p.w *= inv;
    orow[j4] = p;
    u16x4 b;
    b[0] = f2bf(p.x); b[1] = f2bf(p.y); b[2] = f2bf(p.z); b[3] = f2bf(p.w);
    *(u16x4*)(obrow + j4 * 4) = b;
  }
}

// ---------------- layer-2 masked softmax (bits mask) + bf16 dual write ----------------
__global__ __launch_bounds__(256) void att_softmax2_k(
    const unsigned* __restrict__ bits, const float* __restrict__ e1,
    const float* __restrict__ e2, float* __restrict__ att,
    unsigned short* __restrict__ attb)
{
  __shared__ unsigned bw[256];
  __shared__ float red[4];
  int i = blockIdx.x, t = threadIdx.x;
  bw[t] = bits[(size_t)i * 256 + t];
  float e1i = e1[i];
  __syncthreads();
  float4 vv[8];
  float s = 0.f;
#pragma unroll
  for (int it = 0; it < 8; ++it) {
    int j4 = t + it * 256;
    float4 ev = *(const float4*)(e2 + j4 * 4);
    unsigned wb = bw[j4 >> 3];
    int b0 = (j4 & 7) * 4;
    float e, p0, p1, p2, p3;
    e = e1i + ev.x; e = e > 0.f ? e : LRELU_ALPHA * e; p0 = ((wb >> (b0 + 0)) & 1) ? __expf(e) : 0.f;
    e = e1i + ev.y; e = e > 0.f ? e : LRELU_ALPHA * e; p1 = ((wb >> (b0 + 1)) & 1) ? __expf(e) : 0.f;
    e = e1i + ev.z; e = e > 0.f ? e : LRELU_ALPHA * e; p2 = ((wb >> (b0 + 2)) & 1) ? __expf(e) : 0.f;
    e = e1i + ev.w; e = e > 0.f ? e : LRELU_ALPHA * e; p3 = ((wb >> (b0 + 3)) & 1) ? __expf(e) : 0.f;
    vv[it] = make_float4(p0, p1, p2, p3);
    s += (p0 + p1) + (p2 + p3);
  }
#pragma unroll
  for (int off = 32; off; off >>= 1) s += __shfl_xor(s, off);
  if ((t & 63) == 0) red[t >> 6] = s;
  __syncthreads();
  s = red[0] + red[1] + red[2] + red[3];
  float inv = 1.f / s;
  float4* orow = (float4*)(att + (size_t)i * 8192);
  unsigned short* obrow = attb + (size_t)i * 8192;
#pragma unroll
  for (int it = 0; it < 8; ++it) {
    int j4 = t + it * 256;
    float4 p = vv[it];
    p.x *= inv; p.y *= inv; p.z *= inv; p.w *= inv;
    orow[j4] = p;
    u16x4 b;
    b[0] = f2bf(p.x); b[1] = f2bf(p.y); b[2] = f2bf(p.z); b[3] = f2bf(p.w);
    *(u16x4*)(obrow + j4 * 4) = b;
  }
}

// ---------------- MFMA bf16 GEMM (bf16 A): part[z] = A_bf16 @ BT^T ----------------
// R12-verified structure. BM=64, BK=64, 4 waves. BN=64: 2x2 waves (FM=FN=2).
// BN=16: 4x1 waves (FM=FN=1). A staged as raw bf16 (no converts).
template<int BN, int SPLITK>
__global__ __launch_bounds__(256) void gemm_bfA_k(
    const unsigned short* __restrict__ A,    // [8192][8192] bf16
    const unsigned short* __restrict__ BT,   // [Nc][8192] bf16
    float* __restrict__ part, int ldc)       // [SPLITK][8192][ldc]
{
  constexpr int BM = 64, BK = 64;
  constexpr int WN = (BN == 64) ? 2 : 1;
  constexpr int WROWS = (BN == 64) ? 32 : 16;
  constexpr int WCOLS = (BN == 64) ? 32 : 16;
  constexpr int FM = WROWS / 16;
  constexpr int FN = WCOLS / 16;
  __shared__ __align__(16) char As[BM * 128];
  __shared__ __align__(16) char Bs[BN * 128];
  int t = threadIdx.x;
  int row0 = blockIdx.x * BM;
  int col0 = blockIdx.y * BN;
  int z = blockIdx.z;
  int ntk = 128 / SPLITK;
  int kt0 = z * ntk, kt1 = kt0 + ntk;
  int w = t >> 6, l = t & 63;
  int wm = w / WN, wn = w % WN;

  f32x4 acc[FM][FN] = {};

  int ar = t >> 2, aseg = t & 3;   // A: 64 rows x 4 segs of 16 bf16
  int swzA = (ar & 7) << 4;
  const unsigned short* agp = A + (size_t)(row0 + ar) * 8192 + aseg * 16;

  for (int kt = kt0; kt < kt1; ++kt) {
    __syncthreads();
    { // stage A (bf16 direct, swizzled)
      const u16x8* src = (const u16x8*)(agp + kt * BK);
      u16x8 c0 = src[0], c1 = src[1];
      int base = ar * 128 + aseg * 32;
      *(u16x8*)(As + ((base) ^ swzA)) = c0;
      *(u16x8*)(As + ((base + 16) ^ swzA)) = c1;
    }
    if constexpr (BN == 64) { // stage B: 64 rows x 64 bf16
      int br = t >> 2, seg = t & 3;
      const u16x8* src = (const u16x8*)(BT + (size_t)(col0 + br) * 8192 + kt * BK + seg * 16);
      u16x8 b0 = src[0], b1 = src[1];
      int base = br * 128 + seg * 32;
      int swz = (br & 7) << 4;
      *(u16x8*)(Bs + ((base) ^ swz)) = b0;
      *(u16x8*)(Bs + ((base + 16) ^ swz)) = b1;
    } else {                  // BN==16: 16 rows x 64 bf16
      int br = t >> 4, seg = t & 15;
      const u16x4* src = (const u16x4*)(BT + (size_t)(col0 + br) * 8192 + kt * BK + seg * 4);
      u16x4 b0 = src[0];
      int base = br * 128 + seg * 8;
      int swz = (br & 7) << 4;
      *(u16x4*)(Bs + (base ^ swz)) = b0;
    }
    __syncthreads();
#pragma unroll
    for (int kk = 0; kk < BK; kk += 32) {
      bf16x8 af[FM], bfr[FN];
      int kb = (kk + (l >> 4) * 8) * 2;
#pragma unroll
      for (int fm = 0; fm < FM; ++fm) {
        int r = wm * WROWS + fm * 16 + (l & 15);
        af[fm] = *(const bf16x8*)(As + ((r * 128 + kb) ^ ((r & 7) << 4)));
      }
#pragma unroll
      for (int fn = 0; fn < FN; ++fn) {
        int c = wn * WCOLS + fn * 16 + (l & 15);
        bfr[fn] = *(const bf16x8*)(Bs + ((c * 128 + kb) ^ ((c & 7) << 4)));
      }
#pragma unroll
      for (int fm = 0; fm < FM; ++fm)
#pragma unroll
        for (int fn = 0; fn < FN; ++fn)
          acc[fm][fn] = __builtin_amdgcn_mfma_f32_16x16x32_bf16(af[fm], bfr[fn], acc[fm][fn], 0, 0, 0);
    }
  }
  // epilogue: C/D layout col=lane&15, row=(lane>>4)*4+reg
#pragma unroll
  for (int fm = 0; fm < FM; ++fm) {
#pragma unroll
    for (int fn = 0; fn < FN; ++fn) {
#pragma unroll
      for (int r = 0; r < 4; ++r) {
        int grow = row0 + wm * WROWS + fm * 16 + (l >> 4) * 4 + r;
        int gcol = col0 + wn * WCOLS + fn * 16 + (l & 15);
        part[((size_t)z * 8192 + grow) * ldc + gcol] = acc[fm][fn][r];
      }
    }
  }
}

// ---------------- small GEMM: Wh2[M][16] = h1[M][256] @ W2[256][16] ----------------
__global__ __launch_bounds__(256) void gemm_small_k(
    const float* __restrict__ A, const float* __restrict__ B,
    float* __restrict__ C, int K, int Ncols)
{
  int t = threadIdx.x;
  int r = blockIdx.x * 16 + (t >> 4);
  int c = t & 15;
  const float* arow = A + (size_t)r * K;
  float acc = 0.f;
#pragma unroll 8
  for (int k = 0; k < K; ++k)
    acc = fmaf(arow[k], B[k * Ncols + c], acc);
  C[(size_t)r * Ncols + c] = acc;
}

// ---------------- split-K reduce + ELU (4 partials) ----------------
__global__ void reduce_elu_k(const float* __restrict__ part, float* __restrict__ out, int total)
{
  int i = blockIdx.x * 256 + threadIdx.x;
  if (i < total) {
    float s = (part[i] + part[total + i]) + (part[2 * (size_t)total + i] + part[3 * (size_t)total + i]);
    out[i] = s > 0.f ? s : expm1f(s);
  }
}

// ---------------- split-K reduce + sigmoid (4 partials) ----------------
__global__ void reduce_sig_k(const float* __restrict__ part, float* __restrict__ out, int total)
{
  int i = blockIdx.x * 256 + threadIdx.x;
  if (i < total) {
    float s = part[i] + part[total + i] + part[2 * (size_t)total + i] + part[3 * (size_t)total + i];
    out[i] = 1.f / (1.f + __expf(-s));
  }
}

extern "C" void kernel_launch(void* const* d_in, const int* in_sizes, int n_in,
                              void* d_out, int out_size, void* d_ws, size_t ws_size,
                              hipStream_t stream)
{
  const float* x   = (const float*)d_in[0];
  const int*   adj = (const int*)d_in[1];
  const float* W1  = (const float*)d_in[2];
  const float* a1  = (const float*)d_in[3];
  const float* W2  = (const float*)d_in[4];
  const float* a2  = (const float*)d_in[5];

  float* out  = (float*)d_out;                 // [8192*16]
  float* h1   = out + 131072;                  // [8192*256]
  float* att1 = h1 + 2097152;                  // [8192*8192]
  float* att2 = att1 + 67108864;               // [8192*8192]

  float* ws = (float*)d_ws;
  float* wh1 = ws;                                            // 2097152 f
  unsigned short* bt1 = (unsigned short*)(wh1 + 2097152);     // 2097152 u16
  float* e1a = wh1 + 2097152 + 1048576;
  float* e2a = e1a + 8192;
  float* wh2 = e2a + 8192;                                    // 131072 f
  unsigned short* bt2 = (unsigned short*)(wh2 + 131072);      // 131072 u16
  float* e1b = wh2 + 131072 + 65536;
  float* e2b = e1b + 8192;
  float* part2 = e2b + 8192;                                  // 4*131072 f
  unsigned* bits = (unsigned*)(part2 + 524288);               // 2097152 u32
  float* part1 = (float*)(bits + 2097152);                    // 4*2097152 f
  unsigned short* att1b = (unsigned short*)(part1 + 8388608); // 67108864 u16
  unsigned short* att2b = att1b + 67108864;                   // 67108864 u16

  // ---- layer 1 ----
  gemm_f32_k<<<dim3(64, 4), 256, 0, stream>>>(x, W1, wh1, 8192, 512, 256);
  calc_e_k<<<2048, 256, 0, stream>>>(wh1, a1, e1a, e2a, 256);
  transpose_bf16_k<<<dim3(8, 256), dim3(32, 8), 0, stream>>>(wh1, bt1, 8192, 256);
  att_softmax1_k<<<8192, 256, 0, stream>>>(adj, e1a, e2a, att1, att1b, bits);
  gemm_bfA_k<64, 4><<<dim3(128, 4, 4), 256, 0, stream>>>(att1b, bt1, part1, 256);
  reduce_elu_k<<<8192, 256, 0, stream>>>(part1, h1, 2097152);

  // ---- layer 2 ----
  gemm_small_k<<<512, 256, 0, stream>>>(h1, W2, wh2, 256, 16);
  calc_e_k<<<2048, 256, 0, stream>>>(wh2, a2, e1b, e2b, 16);
  transpose_bf16_k<<<dim3(1, 256), dim3(32, 8), 0, stream>>>(wh2, bt2, 8192, 16);
  att_softmax2_k<<<8192, 256, 0, stream>>>(bits, e1b, e2b, att2, att2b);
  gemm_bfA_k<16, 4><<<dim3(128, 1, 4), 256, 0, stream>>>(att2b, bt2, part2, 16);
  reduce_sig_k<<<512, 256, 0, stream>>>(part2, out, 131072);
}

// Round 14
// 424.910 us; speedup vs baseline: 1.0777x; 1.0777x over previous
//
#include <hip/hip_runtime.h>
#include <hip/hip_bf16.h>

#define LRELU_ALPHA 0.2f

typedef __attribute__((ext_vector_type(8))) __bf16 bf16x8;
typedef __attribute__((ext_vector_type(4))) float f32x4;
typedef __attribute__((ext_vector_type(8))) unsigned short u16x8;
typedef __attribute__((ext_vector_type(4))) unsigned short u16x4;

__device__ __forceinline__ unsigned short f2bf(float f) {
  unsigned int u = __float_as_uint(f);
  u += 0x7fffu + ((u >> 16) & 1u);   // round-to-nearest-even
  return (unsigned short)(u >> 16);
}

// ---------------- fp32 tiled GEMM: wh1 = x @ W1 ----------------
__global__ __launch_bounds__(256) void gemm_f32_k(
    const float* __restrict__ A, const float* __restrict__ B,
    float* __restrict__ C, int M, int K, int Ncols)
{
  __shared__ float As[128][17];
  __shared__ float Bs[16][65];
  int t = threadIdx.x;
  int row0 = blockIdx.x * 128;
  int col0 = blockIdx.y * 64;
  int ty = t >> 4, tx = t & 15;
  float acc[8][4];
#pragma unroll
  for (int i = 0; i < 8; ++i)
#pragma unroll
    for (int j = 0; j < 4; ++j) acc[i][j] = 0.f;

  for (int kt = 0; kt < K; kt += 16) {
    __syncthreads();
    {
      int r = t >> 1, h = t & 1;
      const float4* src = (const float4*)(A + (size_t)(row0 + r) * K + kt + h * 8);
      float4 v0 = src[0], v1 = src[1];
      float* dst = &As[r][h * 8];
      dst[0]=v0.x; dst[1]=v0.y; dst[2]=v0.z; dst[3]=v0.w;
      dst[4]=v1.x; dst[5]=v1.y; dst[6]=v1.z; dst[7]=v1.w;
    }
    {
      int kr = t >> 4, seg = t & 15;
      const float4* src = (const float4*)(B + (size_t)(kt + kr) * Ncols + col0 + seg * 4);
      float4 v = src[0];
      float* dst = &Bs[kr][seg * 4];
      dst[0]=v.x; dst[1]=v.y; dst[2]=v.z; dst[3]=v.w;
    }
    __syncthreads();
#pragma unroll
    for (int k = 0; k < 16; ++k) {
      float bb[4];
#pragma unroll
      for (int j = 0; j < 4; ++j) bb[j] = Bs[k][tx * 4 + j];
#pragma unroll
      for (int i = 0; i < 8; ++i) {
        float aa = As[ty * 8 + i][k];
#pragma unroll
        for (int j = 0; j < 4; ++j) acc[i][j] = fmaf(aa, bb[j], acc[i][j]);
      }
    }
  }
#pragma unroll
  for (int i = 0; i < 8; ++i) {
    float4 v = make_float4(acc[i][0], acc[i][1], acc[i][2], acc[i][3]);
    *(float4*)(C + (size_t)(row0 + ty * 8 + i) * Ncols + col0 + tx * 4) = v;
  }
}

// ---------------- e1/e2 vectors (layer 1): wave per row ----------------
__global__ __launch_bounds__(256) void calc_e_k(
    const float* __restrict__ Wh, const float* __restrict__ a,
    float* __restrict__ e1, float* __restrict__ e2, int F)
{
  int row = blockIdx.x * 4 + (threadIdx.x >> 6);
  int l = threadIdx.x & 63;
  const float* r = Wh + (size_t)row * F;
  float s1 = 0.f, s2 = 0.f;
  for (int f = l; f < F; f += 64) {
    float v = r[f];
    s1 += v * a[f];
    s2 += v * a[F + f];
  }
#pragma unroll
  for (int off = 32; off; off >>= 1) {
    s1 += __shfl_down(s1, off);
    s2 += __shfl_down(s2, off);
  }
  if (l == 0) { e1[row] = s1; e2[row] = s2; }
}

// ---------------- transpose + fp32->bf16 (bt1): out[c][r] = bf16(in[r][c]) ----------------
__global__ void transpose_bf16_k(const float* __restrict__ in, unsigned short* __restrict__ out,
                                 int R, int Cc)
{
  __shared__ float tile[32][33];
  int tx = threadIdx.x, ty = threadIdx.y;
  int c0 = blockIdx.x * 32, r0 = blockIdx.y * 32;
  int c = c0 + tx;
  if (c < Cc) {
    for (int i = ty; i < 32; i += 8)
      tile[i][tx] = in[(size_t)(r0 + i) * Cc + c];
  }
  __syncthreads();
  int r = r0 + tx;
  for (int i = ty; i < 32; i += 8) {
    int cc = c0 + i;
    if (cc < Cc)
      out[(size_t)cc * R + r] = f2bf(tile[tx][i]);
  }
}

// ---------------- layer-1 masked softmax + inline adj bit-pack + bf16 dual write ----------------
__global__ __launch_bounds__(256) void att_softmax1_k(
    const int* __restrict__ adj, const float* __restrict__ e1,
    const float* __restrict__ e2, float* __restrict__ att,
    unsigned short* __restrict__ attb, unsigned* __restrict__ bits)
{
  __shared__ float red[4];
  int i = blockIdx.x, t = threadIdx.x;
  const int4* arow = (const int4*)(adj + (size_t)i * 8192);
  unsigned* brow = bits + (size_t)i * 256;
  float e1i = e1[i];
  float4 vv[8];
  float s = 0.f;
#pragma unroll
  for (int it = 0; it < 8; ++it) {
    int j4 = t + it * 256;               // int4/float4 index
    int4 a4 = arow[j4];
    float4 ev = *(const float4*)(e2 + j4 * 4);
    unsigned n = (unsigned)(a4.x > 0) | ((unsigned)(a4.y > 0) << 1)
               | ((unsigned)(a4.z > 0) << 2) | ((unsigned)(a4.w > 0) << 3);
    unsigned v = n << ((t & 7) * 4);
    v |= __shfl_xor(v, 1);
    v |= __shfl_xor(v, 2);
    v |= __shfl_xor(v, 4);
    if ((t & 7) == 0) brow[it * 32 + (t >> 3)] = v;
    float e, p0, p1, p2, p3;
    e = e1i + ev.x; e = e > 0.f ? e : LRELU_ALPHA * e; p0 = (a4.x > 0) ? __expf(e) : 0.f;
    e = e1i + ev.y; e = e > 0.f ? e : LRELU_ALPHA * e; p1 = (a4.y > 0) ? __expf(e) : 0.f;
    e = e1i + ev.z; e = e > 0.f ? e : LRELU_ALPHA * e; p2 = (a4.z > 0) ? __expf(e) : 0.f;
    e = e1i + ev.w; e = e > 0.f ? e : LRELU_ALPHA * e; p3 = (a4.w > 0) ? __expf(e) : 0.f;
    vv[it] = make_float4(p0, p1, p2, p3);
    s += (p0 + p1) + (p2 + p3);
  }
#pragma unroll
  for (int off = 32; off; off >>= 1) s += __shfl_xor(s, off);
  if ((t & 63) == 0) red[t >> 6] = s;
  __syncthreads();
  s = red[0] + red[1] + red[2] + red[3];
  float inv = 1.f / s;
  float4* orow = (float4*)(att + (size_t)i * 8192);
  unsigned short* obrow = attb + (size_t)i * 8192;
#pragma unroll
  for (int it = 0; it < 8; ++it) {
    int j4 = t + it * 256;
    float4 p = vv[it];
    p.x *= inv; p.y *= inv; p.z *= inv; p.w *= inv;
    orow[j4] = p;
    u16x4 b;
    b[0] = f2bf(p.x); b[1] = f2bf(p.y); b[2] = f2bf(p.z); b[3] = f2bf(p.w);
    *(u16x4*)(obrow + j4 * 4) = b;
  }
}

// ---------------- layer-2 masked softmax (bits mask), fp32 out only ----------------
__global__ __launch_bounds__(256) void att_softmax2_k(
    const unsigned* __restrict__ bits, const float* __restrict__ e1,
    const float* __restrict__ e2, float* __restrict__ att)
{
  __shared__ unsigned bw[256];
  __shared__ float red[4];
  int i = blockIdx.x, t = threadIdx.x;
  bw[t] = bits[(size_t)i * 256 + t];
  float e1i = e1[i];
  __syncthreads();
  float4 vv[8];
  float s = 0.f;
#pragma unroll
  for (int it = 0; it < 8; ++it) {
    int j4 = t + it * 256;
    float4 ev = *(const float4*)(e2 + j4 * 4);
    unsigned wb = bw[j4 >> 3];
    int b0 = (j4 & 7) * 4;
    float e, p0, p1, p2, p3;
    e = e1i + ev.x; e = e > 0.f ? e : LRELU_ALPHA * e; p0 = ((wb >> (b0 + 0)) & 1) ? __expf(e) : 0.f;
    e = e1i + ev.y; e = e > 0.f ? e : LRELU_ALPHA * e; p1 = ((wb >> (b0 + 1)) & 1) ? __expf(e) : 0.f;
    e = e1i + ev.z; e = e > 0.f ? e : LRELU_ALPHA * e; p2 = ((wb >> (b0 + 2)) & 1) ? __expf(e) : 0.f;
    e = e1i + ev.w; e = e > 0.f ? e : LRELU_ALPHA * e; p3 = ((wb >> (b0 + 3)) & 1) ? __expf(e) : 0.f;
    vv[it] = make_float4(p0, p1, p2, p3);
    s += (p0 + p1) + (p2 + p3);
  }
#pragma unroll
  for (int off = 32; off; off >>= 1) s += __shfl_xor(s, off);
  if ((t & 63) == 0) red[t >> 6] = s;
  __syncthreads();
  s = red[0] + red[1] + red[2] + red[3];
  float inv = 1.f / s;
  float4* orow = (float4*)(att + (size_t)i * 8192);
#pragma unroll
  for (int it = 0; it < 8; ++it) {
    float4 p = vv[it];
    p.x *= inv; p.y *= inv; p.z *= inv; p.w *= inv;
    orow[t + it * 256] = p;
  }
}

// ---------------- MFMA bf16 GEMM (bf16 A, layer 1): part[z] = att1b @ bt1^T ----------------
__global__ __launch_bounds__(256) void gemm_bfA_k(
    const unsigned short* __restrict__ A,    // [8192][8192] bf16
    const unsigned short* __restrict__ BT,   // [256][8192] bf16
    float* __restrict__ part)                // [4][8192][256]
{
  constexpr int BM = 64, BN = 64, BK = 64;
  __shared__ __align__(16) char As[BM * 128];
  __shared__ __align__(16) char Bs[BN * 128];
  int t = threadIdx.x;
  int row0 = blockIdx.x * BM;
  int col0 = blockIdx.y * BN;
  int z = blockIdx.z;
  int kt0 = z * 32, kt1 = kt0 + 32;
  int w = t >> 6, l = t & 63;
  int wm = w >> 1, wn = w & 1;

  f32x4 acc[2][2] = {};

  int ar = t >> 2, aseg = t & 3;   // A: 64 rows x 4 segs of 16 bf16
  int swzA = (ar & 7) << 4;
  const unsigned short* agp = A + (size_t)(row0 + ar) * 8192 + aseg * 16;

  for (int kt = kt0; kt < kt1; ++kt) {
    __syncthreads();
    { // stage A (bf16 direct, swizzled)
      const u16x8* src = (const u16x8*)(agp + kt * BK);
      u16x8 c0 = src[0], c1 = src[1];
      int base = ar * 128 + aseg * 32;
      *(u16x8*)(As + ((base) ^ swzA)) = c0;
      *(u16x8*)(As + ((base + 16) ^ swzA)) = c1;
    }
    { // stage B: 64 rows x 64 bf16
      int br = t >> 2, seg = t & 3;
      const u16x8* src = (const u16x8*)(BT + (size_t)(col0 + br) * 8192 + kt * BK + seg * 16);
      u16x8 b0 = src[0], b1 = src[1];
      int base = br * 128 + seg * 32;
      int swz = (br & 7) << 4;
      *(u16x8*)(Bs + ((base) ^ swz)) = b0;
      *(u16x8*)(Bs + ((base + 16) ^ swz)) = b1;
    }
    __syncthreads();
#pragma unroll
    for (int kk = 0; kk < BK; kk += 32) {
      bf16x8 af[2], bfr[2];
      int kb = (kk + (l >> 4) * 8) * 2;
#pragma unroll
      for (int fm = 0; fm < 2; ++fm) {
        int r = wm * 32 + fm * 16 + (l & 15);
        af[fm] = *(const bf16x8*)(As + ((r * 128 + kb) ^ ((r & 7) << 4)));
      }
#pragma unroll
      for (int fn = 0; fn < 2; ++fn) {
        int c = wn * 32 + fn * 16 + (l & 15);
        bfr[fn] = *(const bf16x8*)(Bs + ((c * 128 + kb) ^ ((c & 7) << 4)));
      }
#pragma unroll
      for (int fm = 0; fm < 2; ++fm)
#pragma unroll
        for (int fn = 0; fn < 2; ++fn)
          acc[fm][fn] = __builtin_amdgcn_mfma_f32_16x16x32_bf16(af[fm], bfr[fn], acc[fm][fn], 0, 0, 0);
    }
  }
#pragma unroll
  for (int fm = 0; fm < 2; ++fm) {
#pragma unroll
    for (int fn = 0; fn < 2; ++fn) {
#pragma unroll
      for (int r = 0; r < 4; ++r) {
        int grow = row0 + wm * 32 + fm * 16 + (l >> 4) * 4 + r;
        int gcol = col0 + wn * 32 + fn * 16 + (l & 15);
        part[((size_t)z * 8192 + grow) * 256 + gcol] = acc[fm][fn][r];
      }
    }
  }
}

// ---------------- fused layer boundary: part1 -> h1 (ELU) -> wh2 -> bt2 + e1b/e2b ----------------
// 512 blocks x 256 thr, 16 rows each. Replaces reduce_elu + gemm_small +
// transpose_bf16(bt2) + calc_e(layer2). Same arithmetic, 3 fewer launches,
// no wh2/h1 HBM round trips.
__global__ __launch_bounds__(256) void epilogue2_k(
    const float* __restrict__ part, const float* __restrict__ W2,
    const float* __restrict__ a2, float* __restrict__ h1,
    unsigned short* __restrict__ bt2, float* __restrict__ e1b,
    float* __restrict__ e2b)
{
  __shared__ float w2s[256][17];
  __shared__ float h1s[4096];
  int t = threadIdx.x;
  int row0 = blockIdx.x * 16;
  { // load W2 [256][16]
    const float4* src = (const float4*)(W2 + t * 16);
    float4 v0 = src[0], v1 = src[1], v2 = src[2], v3 = src[3];
    float* d = &w2s[t][0];
    d[0]=v0.x; d[1]=v0.y; d[2]=v0.z; d[3]=v0.w;
    d[4]=v1.x; d[5]=v1.y; d[6]=v1.z; d[7]=v1.w;
    d[8]=v2.x; d[9]=v2.y; d[10]=v2.z; d[11]=v2.w;
    d[12]=v3.x; d[13]=v3.y; d[14]=v3.z; d[15]=v3.w;
  }
  // split-K reduce + ELU -> h1 (global + LDS)
  size_t base = (size_t)row0 * 256;
#pragma unroll
  for (int it = 0; it < 16; ++it) {
    int e = t + it * 256;
    float s = (part[base + e] + part[2097152 + base + e])
            + (part[2 * 2097152 + base + e] + part[3 * 2097152 + base + e]);
    float h = s > 0.f ? s : expm1f(s);
    h1[base + e] = h;
    h1s[e] = h;
  }
  __syncthreads();
  // wh2 = h1 @ W2  (thread (r,c))
  int r = t >> 4, c = t & 15;
  const float* hrow = &h1s[r * 256];
  float acc = 0.f;
#pragma unroll 8
  for (int k = 0; k < 256; ++k)
    acc = fmaf(hrow[k], w2s[k][c], acc);
  bt2[(size_t)c * 8192 + row0 + r] = f2bf(acc);
  // e1b/e2b: 16-lane reduce (xor<16 stays in group)
  float v1 = acc * a2[c];
  float v2 = acc * a2[16 + c];
#pragma unroll
  for (int off = 8; off; off >>= 1) {
    v1 += __shfl_xor(v1, off);
    v2 += __shfl_xor(v2, off);
  }
  if (c == 0) { e1b[row0 + r] = v1; e2b[row0 + r] = v2; }
}

// ---------------- MFMA bf16 GEMM (layer 2, fp32 A): part2[z] = att2 @ bt2^T ----------------
__global__ __launch_bounds__(256) void gemm_mfma2_k(
    const float* __restrict__ A, const unsigned short* __restrict__ BT,
    float* __restrict__ part)
{
  constexpr int BM = 64, BN = 16, BK = 64;
  __shared__ __align__(16) char As[BM * 128];
  __shared__ __align__(16) char Bs[BN * 128];
  int t = threadIdx.x;
  int row0 = blockIdx.x * BM;
  int z = blockIdx.z;
  int kt0 = z * 32, kt1 = kt0 + 32;
  int w = t >> 6, l = t & 63;

  f32x4 acc = {};

  int ar = t >> 2, aseg = t & 3;
  int swzA = (ar & 7) << 4;

  for (int kt = kt0; kt < kt1; ++kt) {
    __syncthreads();
    {
      const float4* src = (const float4*)(A + (size_t)(row0 + ar) * 8192 + kt * BK + aseg * 16);
      float4 v0 = src[0], v1 = src[1], v2 = src[2], v3 = src[3];
      u16x8 c0, c1;
      c0[0]=f2bf(v0.x); c0[1]=f2bf(v0.y); c0[2]=f2bf(v0.z); c0[3]=f2bf(v0.w);
      c0[4]=f2bf(v1.x); c0[5]=f2bf(v1.y); c0[6]=f2bf(v1.z); c0[7]=f2bf(v1.w);
      c1[0]=f2bf(v2.x); c1[1]=f2bf(v2.y); c1[2]=f2bf(v2.z); c1[3]=f2bf(v2.w);
      c1[4]=f2bf(v3.x); c1[5]=f2bf(v3.y); c1[6]=f2bf(v3.z); c1[7]=f2bf(v3.w);
      int base = ar * 128 + aseg * 32;
      *(u16x8*)(As + ((base) ^ swzA)) = c0;
      *(u16x8*)(As + ((base + 16) ^ swzA)) = c1;
    }
    {
      int br = t >> 4, seg = t & 15;
      const u16x4* src = (const u16x4*)(BT + (size_t)br * 8192 + kt * BK + seg * 4);
      u16x4 b0 = src[0];
      int base = br * 128 + seg * 8;
      int swz = (br & 7) << 4;
      *(u16x4*)(Bs + (base ^ swz)) = b0;
    }
    __syncthreads();
#pragma unroll
    for (int kk = 0; kk < BK; kk += 32) {
      int kb = (kk + (l >> 4) * 8) * 2;
      int r = w * 16 + (l & 15);
      bf16x8 af = *(const bf16x8*)(As + ((r * 128 + kb) ^ ((r & 7) << 4)));
      int c = l & 15;
      bf16x8 bf = *(const bf16x8*)(Bs + ((c * 128 + kb) ^ ((c & 7) << 4)));
      acc = __builtin_amdgcn_mfma_f32_16x16x32_bf16(af, bf, acc, 0, 0, 0);
    }
  }
#pragma unroll
  for (int r = 0; r < 4; ++r) {
    int grow = row0 + w * 16 + (l >> 4) * 4 + r;
    int gcol = l & 15;
    part[((size_t)z * 8192 + grow) * 16 + gcol] = acc[r];
  }
}

// ---------------- split-K reduce + sigmoid (4 partials) ----------------
__global__ void reduce_sig_k(const float* __restrict__ part, float* __restrict__ out, int total)
{
  int i = blockIdx.x * 256 + threadIdx.x;
  if (i < total) {
    float s = part[i] + part[total + i] + part[2 * (size_t)total + i] + part[3 * (size_t)total + i];
    out[i] = 1.f / (1.f + __expf(-s));
  }
}

extern "C" void kernel_launch(void* const* d_in, const int* in_sizes, int n_in,
                              void* d_out, int out_size, void* d_ws, size_t ws_size,
                              hipStream_t stream)
{
  const float* x   = (const float*)d_in[0];
  const int*   adj = (const int*)d_in[1];
  const float* W1  = (const float*)d_in[2];
  const float* a1  = (const float*)d_in[3];
  const float* W2  = (const float*)d_in[4];
  const float* a2  = (const float*)d_in[5];

  float* out  = (float*)d_out;                 // [8192*16]
  float* h1   = out + 131072;                  // [8192*256]
  float* att1 = h1 + 2097152;                  // [8192*8192]
  float* att2 = att1 + 67108864;               // [8192*8192]

  float* ws = (float*)d_ws;
  float* wh1 = ws;                                            // 2097152 f
  unsigned short* bt1 = (unsigned short*)(wh1 + 2097152);     // 2097152 u16
  float* e1a = wh1 + 2097152 + 1048576;
  float* e2a = e1a + 8192;
  unsigned short* bt2 = (unsigned short*)(e2a + 8192);        // 131072 u16
  float* e1b = (float*)(bt2 + 131072);
  float* e2b = e1b + 8192;
  float* part2 = e2b + 8192;                                  // 4*131072 f
  unsigned* bits = (unsigned*)(part2 + 524288);               // 2097152 u32
  float* part1 = (float*)(bits + 2097152);                    // 4*2097152 f
  unsigned short* att1b = (unsigned short*)(part1 + 8388608); // 67108864 u16

  // ---- layer 1 ----
  gemm_f32_k<<<dim3(64, 4), 256, 0, stream>>>(x, W1, wh1, 8192, 512, 256);
  calc_e_k<<<2048, 256, 0, stream>>>(wh1, a1, e1a, e2a, 256);
  transpose_bf16_k<<<dim3(8, 256), dim3(32, 8), 0, stream>>>(wh1, bt1, 8192, 256);
  att_softmax1_k<<<8192, 256, 0, stream>>>(adj, e1a, e2a, att1, att1b, bits);
  gemm_bfA_k<<<dim3(128, 4, 4), 256, 0, stream>>>(att1b, bt1, part1);

  // ---- layer boundary (fused): h1, bt2, e1b/e2b ----
  epilogue2_k<<<512, 256, 0, stream>>>(part1, W2, a2, h1, bt2, e1b, e2b);

  // ---- layer 2 ----
  att_softmax2_k<<<8192, 256, 0, stream>>>(bits, e1b, e2b, att2);
  gemm_mfma2_k<<<dim3(128, 1, 4), 256, 0, stream>>>(att2, bt2, part2);
  reduce_sig_k<<<512, 256, 0, stream>>>(part2, out, 131072);
}

// Round 15
// 418.327 us; speedup vs baseline: 1.0947x; 1.0157x over previous
//
#include <hip/hip_runtime.h>
#include <hip/hip_bf16.h>

#define LRELU_ALPHA 0.2f

typedef __attribute__((ext_vector_type(8))) __bf16 bf16x8;
typedef __attribute__((ext_vector_type(4))) float f32x4;
typedef __attribute__((ext_vector_type(8))) unsigned short u16x8;
typedef __attribute__((ext_vector_type(4))) unsigned short u16x4;

__device__ __forceinline__ unsigned short f2bf(float f) {
  unsigned int u = __float_as_uint(f);
  u += 0x7fffu + ((u >> 16) & 1u);   // round-to-nearest-even
  return (unsigned short)(u >> 16);
}

__device__ __forceinline__ void gload16(const void* g, void* l) {
  __builtin_amdgcn_global_load_lds(
      (const __attribute__((address_space(1))) void*)g,
      (__attribute__((address_space(3))) void*)l, 16, 0, 0);
}

// ---------------- fp32 tiled GEMM: wh1 = x @ W1 ----------------
__global__ __launch_bounds__(256) void gemm_f32_k(
    const float* __restrict__ A, const float* __restrict__ B,
    float* __restrict__ C, int M, int K, int Ncols)
{
  __shared__ float As[128][17];
  __shared__ float Bs[16][65];
  int t = threadIdx.x;
  int row0 = blockIdx.x * 128;
  int col0 = blockIdx.y * 64;
  int ty = t >> 4, tx = t & 15;
  float acc[8][4];
#pragma unroll
  for (int i = 0; i < 8; ++i)
#pragma unroll
    for (int j = 0; j < 4; ++j) acc[i][j] = 0.f;

  for (int kt = 0; kt < K; kt += 16) {
    __syncthreads();
    {
      int r = t >> 1, h = t & 1;
      const float4* src = (const float4*)(A + (size_t)(row0 + r) * K + kt + h * 8);
      float4 v0 = src[0], v1 = src[1];
      float* dst = &As[r][h * 8];
      dst[0]=v0.x; dst[1]=v0.y; dst[2]=v0.z; dst[3]=v0.w;
      dst[4]=v1.x; dst[5]=v1.y; dst[6]=v1.z; dst[7]=v1.w;
    }
    {
      int kr = t >> 4, seg = t & 15;
      const float4* src = (const float4*)(B + (size_t)(kt + kr) * Ncols + col0 + seg * 4);
      float4 v = src[0];
      float* dst = &Bs[kr][seg * 4];
      dst[0]=v.x; dst[1]=v.y; dst[2]=v.z; dst[3]=v.w;
    }
    __syncthreads();
#pragma unroll
    for (int k = 0; k < 16; ++k) {
      float bb[4];
#pragma unroll
      for (int j = 0; j < 4; ++j) bb[j] = Bs[k][tx * 4 + j];
#pragma unroll
      for (int i = 0; i < 8; ++i) {
        float aa = As[ty * 8 + i][k];
#pragma unroll
        for (int j = 0; j < 4; ++j) acc[i][j] = fmaf(aa, bb[j], acc[i][j]);
      }
    }
  }
#pragma unroll
  for (int i = 0; i < 8; ++i) {
    float4 v = make_float4(acc[i][0], acc[i][1], acc[i][2], acc[i][3]);
    *(float4*)(C + (size_t)(row0 + ty * 8 + i) * Ncols + col0 + tx * 4) = v;
  }
}

// ---------------- e1/e2 vectors (layer 1): wave per row ----------------
__global__ __launch_bounds__(256) void calc_e_k(
    const float* __restrict__ Wh, const float* __restrict__ a,
    float* __restrict__ e1, float* __restrict__ e2, int F)
{
  int row = blockIdx.x * 4 + (threadIdx.x >> 6);
  int l = threadIdx.x & 63;
  const float* r = Wh + (size_t)row * F;
  float s1 = 0.f, s2 = 0.f;
  for (int f = l; f < F; f += 64) {
    float v = r[f];
    s1 += v * a[f];
    s2 += v * a[F + f];
  }
#pragma unroll
  for (int off = 32; off; off >>= 1) {
    s1 += __shfl_down(s1, off);
    s2 += __shfl_down(s2, off);
  }
  if (l == 0) { e1[row] = s1; e2[row] = s2; }
}

// ---------------- transpose + fp32->bf16 (bt1): out[c][r] = bf16(in[r][c]) ----------------
__global__ void transpose_bf16_k(const float* __restrict__ in, unsigned short* __restrict__ out,
                                 int R, int Cc)
{
  __shared__ float tile[32][33];
  int tx = threadIdx.x, ty = threadIdx.y;
  int c0 = blockIdx.x * 32, r0 = blockIdx.y * 32;
  int c = c0 + tx;
  if (c < Cc) {
    for (int i = ty; i < 32; i += 8)
      tile[i][tx] = in[(size_t)(r0 + i) * Cc + c];
  }
  __syncthreads();
  int r = r0 + tx;
  for (int i = ty; i < 32; i += 8) {
    int cc = c0 + i;
    if (cc < Cc)
      out[(size_t)cc * R + r] = f2bf(tile[tx][i]);
  }
}

// ---------------- layer-1 masked softmax + inline adj bit-pack + bf16 dual write ----------------
__global__ __launch_bounds__(256) void att_softmax1_k(
    const int* __restrict__ adj, const float* __restrict__ e1,
    const float* __restrict__ e2, float* __restrict__ att,
    unsigned short* __restrict__ attb, unsigned* __restrict__ bits)
{
  __shared__ float red[4];
  int i = blockIdx.x, t = threadIdx.x;
  const int4* arow = (const int4*)(adj + (size_t)i * 8192);
  unsigned* brow = bits + (size_t)i * 256;
  float e1i = e1[i];
  float4 vv[8];
  float s = 0.f;
#pragma unroll
  for (int it = 0; it < 8; ++it) {
    int j4 = t + it * 256;               // int4/float4 index
    int4 a4 = arow[j4];
    float4 ev = *(const float4*)(e2 + j4 * 4);
    unsigned n = (unsigned)(a4.x > 0) | ((unsigned)(a4.y > 0) << 1)
               | ((unsigned)(a4.z > 0) << 2) | ((unsigned)(a4.w > 0) << 3);
    unsigned v = n << ((t & 7) * 4);
    v |= __shfl_xor(v, 1);
    v |= __shfl_xor(v, 2);
    v |= __shfl_xor(v, 4);
    if ((t & 7) == 0) brow[it * 32 + (t >> 3)] = v;
    float e, p0, p1, p2, p3;
    e = e1i + ev.x; e = e > 0.f ? e : LRELU_ALPHA * e; p0 = (a4.x > 0) ? __expf(e) : 0.f;
    e = e1i + ev.y; e = e > 0.f ? e : LRELU_ALPHA * e; p1 = (a4.y > 0) ? __expf(e) : 0.f;
    e = e1i + ev.z; e = e > 0.f ? e : LRELU_ALPHA * e; p2 = (a4.z > 0) ? __expf(e) : 0.f;
    e = e1i + ev.w; e = e > 0.f ? e : LRELU_ALPHA * e; p3 = (a4.w > 0) ? __expf(e) : 0.f;
    vv[it] = make_float4(p0, p1, p2, p3);
    s += (p0 + p1) + (p2 + p3);
  }
#pragma unroll
  for (int off = 32; off; off >>= 1) s += __shfl_xor(s, off);
  if ((t & 63) == 0) red[t >> 6] = s;
  __syncthreads();
  s = red[0] + red[1] + red[2] + red[3];
  float inv = 1.f / s;
  float4* orow = (float4*)(att + (size_t)i * 8192);
  unsigned short* obrow = attb + (size_t)i * 8192;
#pragma unroll
  for (int it = 0; it < 8; ++it) {
    int j4 = t + it * 256;
    float4 p = vv[it];
    p.x *= inv; p.y *= inv; p.z *= inv; p.w *= inv;
    orow[j4] = p;
    u16x4 b;
    b[0] = f2bf(p.x); b[1] = f2bf(p.y); b[2] = f2bf(p.z); b[3] = f2bf(p.w);
    *(u16x4*)(obrow + j4 * 4) = b;
  }
}

// ---------------- layer-2 masked softmax (bits mask), fp32 out only ----------------
__global__ __launch_bounds__(256) void att_softmax2_k(
    const unsigned* __restrict__ bits, const float* __restrict__ e1,
    const float* __restrict__ e2, float* __restrict__ att)
{
  __shared__ unsigned bw[256];
  __shared__ float red[4];
  int i = blockIdx.x, t = threadIdx.x;
  bw[t] = bits[(size_t)i * 256 + t];
  float e1i = e1[i];
  __syncthreads();
  float4 vv[8];
  float s = 0.f;
#pragma unroll
  for (int it = 0; it < 8; ++it) {
    int j4 = t + it * 256;
    float4 ev = *(const float4*)(e2 + j4 * 4);
    unsigned wb = bw[j4 >> 3];
    int b0 = (j4 & 7) * 4;
    float e, p0, p1, p2, p3;
    e = e1i + ev.x; e = e > 0.f ? e : LRELU_ALPHA * e; p0 = ((wb >> (b0 + 0)) & 1) ? __expf(e) : 0.f;
    e = e1i + ev.y; e = e > 0.f ? e : LRELU_ALPHA * e; p1 = ((wb >> (b0 + 1)) & 1) ? __expf(e) : 0.f;
    e = e1i + ev.z; e = e > 0.f ? e : LRELU_ALPHA * e; p2 = ((wb >> (b0 + 2)) & 1) ? __expf(e) : 0.f;
    e = e1i + ev.w; e = e > 0.f ? e : LRELU_ALPHA * e; p3 = ((wb >> (b0 + 3)) & 1) ? __expf(e) : 0.f;
    vv[it] = make_float4(p0, p1, p2, p3);
    s += (p0 + p1) + (p2 + p3);
  }
#pragma unroll
  for (int off = 32; off; off >>= 1) s += __shfl_xor(s, off);
  if ((t & 63) == 0) red[t >> 6] = s;
  __syncthreads();
  s = red[0] + red[1] + red[2] + red[3];
  float inv = 1.f / s;
  float4* orow = (float4*)(att + (size_t)i * 8192);
#pragma unroll
  for (int it = 0; it < 8; ++it) {
    float4 p = vv[it];
    p.x *= inv; p.y *= inv; p.z *= inv; p.w *= inv;
    orow[t + it * 256] = p;
  }
}

// ---------------- MFMA bf16 GEMM (bf16 A, layer 1): part[z] = att1b @ bt1^T ----------------
// global_load_lds staging: linear LDS dest (HW requirement), per-lane global
// source pre-swizzled (seg ^= row&7) so the stored layout equals the XOR-
// swizzled layout the fragment reads expect (rule: both-sides-or-neither).
// Zero VALU staging; splitK=4 keeps 8 queued blocks/CU for latency hiding.
__global__ __launch_bounds__(256) void gemm_bfA_k(
    const unsigned short* __restrict__ A,    // att1b [8192][8192] bf16
    const unsigned short* __restrict__ BT,   // bt1 [256][8192] bf16
    float* __restrict__ part)                // [4][8192][256]
{
  constexpr int BM = 64, BN = 64, BK = 64;
  __shared__ __align__(16) unsigned short As[BM * 64];   // row stride 128 B
  __shared__ __align__(16) unsigned short Bs[BN * 64];
  int t = threadIdx.x;
  int row0 = blockIdx.x * BM;
  int col0 = blockIdx.y * BN;
  int z = blockIdx.z;
  int kt0 = z * 32, kt1 = kt0 + 32;
  int w = t >> 6, l = t & 63;
  int wm = w >> 1, wn = w & 1;

  f32x4 acc[2][2] = {};

  // staging geometry: wave w owns rows/cols 16w..16w+15 as 2 chunks of 8.
  // lane l -> row offset (l>>3), seg (l&7); global seg pre-swizzled by row&7.
  int ra0 = 16 * w + (l >> 3);
  int ra1 = ra0 + 8;
  int sseg = ((l & 7) ^ (ra0 & 7)) * 8;      // (ra1&7)==(ra0&7)
  const unsigned short* gA0 = A + (size_t)(row0 + ra0) * 8192 + kt0 * BK + sseg;
  const unsigned short* gA1 = A + (size_t)(row0 + ra1) * 8192 + kt0 * BK + sseg;
  const unsigned short* gB0 = BT + (size_t)(col0 + ra0) * 8192 + kt0 * BK + sseg;
  const unsigned short* gB1 = BT + (size_t)(col0 + ra1) * 8192 + kt0 * BK + sseg;
  unsigned short* lA0 = As + (16 * w) * 64;        // wave-uniform chunk bases
  unsigned short* lA1 = As + (16 * w + 8) * 64;
  unsigned short* lB0 = Bs + (16 * w) * 64;
  unsigned short* lB1 = Bs + (16 * w + 8) * 64;

  for (int kt = 0; kt < 32; ++kt) {
    __syncthreads();
    gload16(gA0 + kt * BK, lA0);
    gload16(gA1 + kt * BK, lA1);
    gload16(gB0 + kt * BK, lB0);
    gload16(gB1 + kt * BK, lB1);
    __syncthreads();   // compiler drains vmcnt before barrier -> LDS valid
#pragma unroll
    for (int kk = 0; kk < BK; kk += 32) {
      bf16x8 af[2], bfr[2];
      int kb = (kk + (l >> 4) * 8) * 2;
#pragma unroll
      for (int fm = 0; fm < 2; ++fm) {
        int r = wm * 32 + fm * 16 + (l & 15);
        af[fm] = *(const bf16x8*)((const char*)As + ((r * 128 + kb) ^ ((r & 7) << 4)));
      }
#pragma unroll
      for (int fn = 0; fn < 2; ++fn) {
        int c = wn * 32 + fn * 16 + (l & 15);
        bfr[fn] = *(const bf16x8*)((const char*)Bs + ((c * 128 + kb) ^ ((c & 7) << 4)));
      }
#pragma unroll
      for (int fm = 0; fm < 2; ++fm)
#pragma unroll
        for (int fn = 0; fn < 2; ++fn)
          acc[fm][fn] = __builtin_amdgcn_mfma_f32_16x16x32_bf16(af[fm], bfr[fn], acc[fm][fn], 0, 0, 0);
    }
  }
#pragma unroll
  for (int fm = 0; fm < 2; ++fm) {
#pragma unroll
    for (int fn = 0; fn < 2; ++fn) {
#pragma unroll
      for (int r = 0; r < 4; ++r) {
        int grow = row0 + wm * 32 + fm * 16 + (l >> 4) * 4 + r;
        int gcol = col0 + wn * 32 + fn * 16 + (l & 15);
        part[((size_t)z * 8192 + grow) * 256 + gcol] = acc[fm][fn][r];
      }
    }
  }
}

// ---------------- fused layer boundary: part1 -> h1 (ELU) -> wh2 -> bt2 + e1b/e2b ----------------
__global__ __launch_bounds__(256) void epilogue2_k(
    const float* __restrict__ part, const float* __restrict__ W2,
    const float* __restrict__ a2, float* __restrict__ h1,
    unsigned short* __restrict__ bt2, float* __restrict__ e1b,
    float* __restrict__ e2b)
{
  __shared__ float w2s[256][17];
  __shared__ float h1s[4096];
  int t = threadIdx.x;
  int row0 = blockIdx.x * 16;
  { // load W2 [256][16]
    const float4* src = (const float4*)(W2 + t * 16);
    float4 v0 = src[0], v1 = src[1], v2 = src[2], v3 = src[3];
    float* d = &w2s[t][0];
    d[0]=v0.x; d[1]=v0.y; d[2]=v0.z; d[3]=v0.w;
    d[4]=v1.x; d[5]=v1.y; d[6]=v1.z; d[7]=v1.w;
    d[8]=v2.x; d[9]=v2.y; d[10]=v2.z; d[11]=v2.w;
    d[12]=v3.x; d[13]=v3.y; d[14]=v3.z; d[15]=v3.w;
  }
  size_t base = (size_t)row0 * 256;
#pragma unroll
  for (int it = 0; it < 16; ++it) {
    int e = t + it * 256;
    float s = (part[base + e] + part[2097152 + base + e])
            + (part[2 * 2097152 + base + e] + part[3 * 2097152 + base + e]);
    float h = s > 0.f ? s : expm1f(s);
    h1[base + e] = h;
    h1s[e] = h;
  }
  __syncthreads();
  int r = t >> 4, c = t & 15;
  const float* hrow = &h1s[r * 256];
  float acc = 0.f;
#pragma unroll 8
  for (int k = 0; k < 256; ++k)
    acc = fmaf(hrow[k], w2s[k][c], acc);
  bt2[(size_t)c * 8192 + row0 + r] = f2bf(acc);
  float v1 = acc * a2[c];
  float v2 = acc * a2[16 + c];
#pragma unroll
  for (int off = 8; off; off >>= 1) {
    v1 += __shfl_xor(v1, off);
    v2 += __shfl_xor(v2, off);
  }
  if (c == 0) { e1b[row0 + r] = v1; e2b[row0 + r] = v2; }
}

// ---------------- MFMA bf16 GEMM (layer 2, fp32 A): part2[z] = att2 @ bt2^T ----------------
__global__ __launch_bounds__(256) void gemm_mfma2_k(
    const float* __restrict__ A, const unsigned short* __restrict__ BT,
    float* __restrict__ part)
{
  constexpr int BM = 64, BN = 16, BK = 64;
  __shared__ __align__(16) char As[BM * 128];
  __shared__ __align__(16) char Bs[BN * 128];
  int t = threadIdx.x;
  int row0 = blockIdx.x * BM;
  int z = blockIdx.z;
  int kt0 = z * 32, kt1 = kt0 + 32;
  int w = t >> 6, l = t & 63;

  f32x4 acc = {};

  int ar = t >> 2, aseg = t & 3;
  int swzA = (ar & 7) << 4;

  for (int kt = kt0; kt < kt1; ++kt) {
    __syncthreads();
    {
      const float4* src = (const float4*)(A + (size_t)(row0 + ar) * 8192 + kt * BK + aseg * 16);
      float4 v0 = src[0], v1 = src[1], v2 = src[2], v3 = src[3];
      u16x8 c0, c1;
      c0[0]=f2bf(v0.x); c0[1]=f2bf(v0.y); c0[2]=f2bf(v0.z); c0[3]=f2bf(v0.w);
      c0[4]=f2bf(v1.x); c0[5]=f2bf(v1.y); c0[6]=f2bf(v1.z); c0[7]=f2bf(v1.w);
      c1[0]=f2bf(v2.x); c1[1]=f2bf(v2.y); c1[2]=f2bf(v2.z); c1[3]=f2bf(v2.w);
      c1[4]=f2bf(v3.x); c1[5]=f2bf(v3.y); c1[6]=f2bf(v3.z); c1[7]=f2bf(v3.w);
      int base = ar * 128 + aseg * 32;
      *(u16x8*)(As + ((base) ^ swzA)) = c0;
      *(u16x8*)(As + ((base + 16) ^ swzA)) = c1;
    }
    {
      int br = t >> 4, seg = t & 15;
      const u16x4* src = (const u16x4*)(BT + (size_t)br * 8192 + kt * BK + seg * 4);
      u16x4 b0 = src[0];
      int base = br * 128 + seg * 8;
      int swz = (br & 7) << 4;
      *(u16x4*)(Bs + (base ^ swz)) = b0;
    }
    __syncthreads();
#pragma unroll
    for (int kk = 0; kk < BK; kk += 32) {
      int kb = (kk + (l >> 4) * 8) * 2;
      int r = w * 16 + (l & 15);
      bf16x8 af = *(const bf16x8*)(As + ((r * 128 + kb) ^ ((r & 7) << 4)));
      int c = l & 15;
      bf16x8 bf = *(const bf16x8*)(Bs + ((c * 128 + kb) ^ ((c & 7) << 4)));
      acc = __builtin_amdgcn_mfma_f32_16x16x32_bf16(af, bf, acc, 0, 0, 0);
    }
  }
#pragma unroll
  for (int r = 0; r < 4; ++r) {
    int grow = row0 + w * 16 + (l >> 4) * 4 + r;
    int gcol = l & 15;
    part[((size_t)z * 8192 + grow) * 16 + gcol] = acc[r];
  }
}

// ---------------- split-K reduce + sigmoid (4 partials) ----------------
__global__ void reduce_sig_k(const float* __restrict__ part, float* __restrict__ out, int total)
{
  int i = blockIdx.x * 256 + threadIdx.x;
  if (i < total) {
    float s = part[i] + part[total + i] + part[2 * (size_t)total + i] + part[3 * (size_t)total + i];
    out[i] = 1.f / (1.f + __expf(-s));
  }
}

extern "C" void kernel_launch(void* const* d_in, const int* in_sizes, int n_in,
                              void* d_out, int out_size, void* d_ws, size_t ws_size,
                              hipStream_t stream)
{
  const float* x   = (const float*)d_in[0];
  const int*   adj = (const int*)d_in[1];
  const float* W1  = (const float*)d_in[2];
  const float* a1  = (const float*)d_in[3];
  const float* W2  = (const float*)d_in[4];
  const float* a2  = (const float*)d_in[5];

  float* out  = (float*)d_out;                 // [8192*16]
  float* h1   = out + 131072;                  // [8192*256]
  float* att1 = h1 + 2097152;                  // [8192*8192]
  float* att2 = att1 + 67108864;               // [8192*8192]

  float* ws = (float*)d_ws;
  float* wh1 = ws;                                            // 2097152 f
  unsigned short* bt1 = (unsigned short*)(wh1 + 2097152);     // 2097152 u16
  float* e1a = wh1 + 2097152 + 1048576;
  float* e2a = e1a + 8192;
  unsigned short* bt2 = (unsigned short*)(e2a + 8192);        // 131072 u16
  float* e1b = (float*)(bt2 + 131072);
  float* e2b = e1b + 8192;
  float* part2 = e2b + 8192;                                  // 4*131072 f
  unsigned* bits = (unsigned*)(part2 + 524288);               // 2097152 u32
  float* part1 = (float*)(bits + 2097152);                    // 4*2097152 f
  unsigned short* att1b = (unsigned short*)(part1 + 8388608); // 67108864 u16

  // ---- layer 1 ----
  gemm_f32_k<<<dim3(64, 4), 256, 0, stream>>>(x, W1, wh1, 8192, 512, 256);
  calc_e_k<<<2048, 256, 0, stream>>>(wh1, a1, e1a, e2a, 256);
  transpose_bf16_k<<<dim3(8, 256), dim3(32, 8), 0, stream>>>(wh1, bt1, 8192, 256);
  att_softmax1_k<<<8192, 256, 0, stream>>>(adj, e1a, e2a, att1, att1b, bits);
  gemm_bfA_k<<<dim3(128, 4, 4), 256, 0, stream>>>(att1b, bt1, part1);

  // ---- layer boundary (fused): h1, bt2, e1b/e2b ----
  epilogue2_k<<<512, 256, 0, stream>>>(part1, W2, a2, h1, bt2, e1b, e2b);

  // ---- layer 2 ----
  att_softmax2_k<<<8192, 256, 0, stream>>>(bits, e1b, e2b, att2);
  gemm_mfma2_k<<<dim3(128, 1, 4), 256, 0, stream>>>(att2, bt2, part2);
  reduce_sig_k<<<512, 256, 0, stream>>>(part2, out, 131072);
}

// Round 16
// 382.055 us; speedup vs baseline: 1.1986x; 1.0949x over previous
//
#include <hip/hip_runtime.h>
#include <hip/hip_bf16.h>

#define LRELU_ALPHA 0.2f

typedef __attribute__((ext_vector_type(8))) __bf16 bf16x8;
typedef __attribute__((ext_vector_type(4))) float f32x4;
typedef __attribute__((ext_vector_type(8))) unsigned short u16x8;
typedef __attribute__((ext_vector_type(4))) unsigned short u16x4;

__device__ __forceinline__ unsigned short f2bf(float f) {
  unsigned int u = __float_as_uint(f);
  u += 0x7fffu + ((u >> 16) & 1u);   // round-to-nearest-even
  return (unsigned short)(u >> 16);
}

__device__ __forceinline__ void gload16(const void* g, void* l) {
  __builtin_amdgcn_global_load_lds(
      (const __attribute__((address_space(1))) void*)g,
      (__attribute__((address_space(3))) void*)l, 16, 0, 0);
}

// ---------------- transpose + fp32->bf16: out[c][r] = bf16(in[r][c]) ----------------
__global__ void transpose_bf16_k(const float* __restrict__ in, unsigned short* __restrict__ out,
                                 int R, int Cc)
{
  __shared__ float tile[32][33];
  int tx = threadIdx.x, ty = threadIdx.y;
  int c0 = blockIdx.x * 32, r0 = blockIdx.y * 32;
  int c = c0 + tx;
  if (c < Cc) {
    for (int i = ty; i < 32; i += 8)
      tile[i][tx] = in[(size_t)(r0 + i) * Cc + c];
  }
  __syncthreads();
  int r = r0 + tx;
  for (int i = ty; i < 32; i += 8) {
    int cc = c0 + i;
    if (cc < Cc)
      out[(size_t)cc * R + r] = f2bf(tile[tx][i]);
  }
}

// ---------------- MFMA GEMM: wh1 = x @ W1 (via w1t bf16) ----------------
// BM=BN=64, K=512 (8 kt), 4 waves 2x2, fp32-A staged with f2bf (R9-proven body).
__global__ __launch_bounds__(256) void gemm_wh1_k(
    const float* __restrict__ A,             // x [8192][512]
    const unsigned short* __restrict__ BT,   // w1t [256][512] bf16
    float* __restrict__ C)                   // wh1 [8192][256]
{
  constexpr int BK = 64;
  __shared__ __align__(16) char As[64 * 128];
  __shared__ __align__(16) char Bs[64 * 128];
  int t = threadIdx.x;
  int row0 = blockIdx.x * 64;
  int col0 = blockIdx.y * 64;
  int w = t >> 6, l = t & 63;
  int wm = w >> 1, wn = w & 1;

  f32x4 acc[2][2] = {};

  int ar = t >> 2, aseg = t & 3;
  int swzA = (ar & 7) << 4;

  for (int kt = 0; kt < 8; ++kt) {
    __syncthreads();
    { // stage A (fp32 -> bf16, swizzled)
      const float4* src = (const float4*)(A + (size_t)(row0 + ar) * 512 + kt * BK + aseg * 16);
      float4 v0 = src[0], v1 = src[1], v2 = src[2], v3 = src[3];
      u16x8 c0, c1;
      c0[0]=f2bf(v0.x); c0[1]=f2bf(v0.y); c0[2]=f2bf(v0.z); c0[3]=f2bf(v0.w);
      c0[4]=f2bf(v1.x); c0[5]=f2bf(v1.y); c0[6]=f2bf(v1.z); c0[7]=f2bf(v1.w);
      c1[0]=f2bf(v2.x); c1[1]=f2bf(v2.y); c1[2]=f2bf(v2.z); c1[3]=f2bf(v2.w);
      c1[4]=f2bf(v3.x); c1[5]=f2bf(v3.y); c1[6]=f2bf(v3.z); c1[7]=f2bf(v3.w);
      int base = ar * 128 + aseg * 32;
      *(u16x8*)(As + ((base) ^ swzA)) = c0;
      *(u16x8*)(As + ((base + 16) ^ swzA)) = c1;
    }
    { // stage B
      int br = t >> 2, seg = t & 3;
      const u16x8* src = (const u16x8*)(BT + (size_t)(col0 + br) * 512 + kt * BK + seg * 16);
      u16x8 b0 = src[0], b1 = src[1];
      int base = br * 128 + seg * 32;
      int swz = (br & 7) << 4;
      *(u16x8*)(Bs + ((base) ^ swz)) = b0;
      *(u16x8*)(Bs + ((base + 16) ^ swz)) = b1;
    }
    __syncthreads();
#pragma unroll
    for (int kk = 0; kk < BK; kk += 32) {
      bf16x8 af[2], bfr[2];
      int kb = (kk + (l >> 4) * 8) * 2;
#pragma unroll
      for (int fm = 0; fm < 2; ++fm) {
        int r = wm * 32 + fm * 16 + (l & 15);
        af[fm] = *(const bf16x8*)(As + ((r * 128 + kb) ^ ((r & 7) << 4)));
      }
#pragma unroll
      for (int fn = 0; fn < 2; ++fn) {
        int c = wn * 32 + fn * 16 + (l & 15);
        bfr[fn] = *(const bf16x8*)(Bs + ((c * 128 + kb) ^ ((c & 7) << 4)));
      }
#pragma unroll
      for (int fm = 0; fm < 2; ++fm)
#pragma unroll
        for (int fn = 0; fn < 2; ++fn)
          acc[fm][fn] = __builtin_amdgcn_mfma_f32_16x16x32_bf16(af[fm], bfr[fn], acc[fm][fn], 0, 0, 0);
    }
  }
#pragma unroll
  for (int fm = 0; fm < 2; ++fm) {
#pragma unroll
    for (int fn = 0; fn < 2; ++fn) {
#pragma unroll
      for (int r = 0; r < 4; ++r) {
        int grow = row0 + wm * 32 + fm * 16 + (l >> 4) * 4 + r;
        int gcol = col0 + wn * 32 + fn * 16 + (l & 15);
        C[(size_t)grow * 256 + gcol] = acc[fm][fn][r];
      }
    }
  }
}

// ---------------- e1/e2 vectors (layer 1): wave per row ----------------
__global__ __launch_bounds__(256) void calc_e_k(
    const float* __restrict__ Wh, const float* __restrict__ a,
    float* __restrict__ e1, float* __restrict__ e2, int F)
{
  int row = blockIdx.x * 4 + (threadIdx.x >> 6);
  int l = threadIdx.x & 63;
  const float* r = Wh + (size_t)row * F;
  float s1 = 0.f, s2 = 0.f;
  for (int f = l; f < F; f += 64) {
    float v = r[f];
    s1 += v * a[f];
    s2 += v * a[F + f];
  }
#pragma unroll
  for (int off = 32; off; off >>= 1) {
    s1 += __shfl_down(s1, off);
    s2 += __shfl_down(s2, off);
  }
  if (l == 0) { e1[row] = s1; e2[row] = s2; }
}

// ---------------- layer-1 masked softmax + inline adj bit-pack + bf16 dual write ----------------
__global__ __launch_bounds__(256) void att_softmax1_k(
    const int* __restrict__ adj, const float* __restrict__ e1,
    const float* __restrict__ e2, float* __restrict__ att,
    unsigned short* __restrict__ attb, unsigned* __restrict__ bits)
{
  __shared__ float red[4];
  int i = blockIdx.x, t = threadIdx.x;
  const int4* arow = (const int4*)(adj + (size_t)i * 8192);
  unsigned* brow = bits + (size_t)i * 256;
  float e1i = e1[i];
  float4 vv[8];
  float s = 0.f;
#pragma unroll
  for (int it = 0; it < 8; ++it) {
    int j4 = t + it * 256;               // int4/float4 index
    int4 a4 = arow[j4];
    float4 ev = *(const float4*)(e2 + j4 * 4);
    unsigned n = (unsigned)(a4.x > 0) | ((unsigned)(a4.y > 0) << 1)
               | ((unsigned)(a4.z > 0) << 2) | ((unsigned)(a4.w > 0) << 3);
    unsigned v = n << ((t & 7) * 4);
    v |= __shfl_xor(v, 1);
    v |= __shfl_xor(v, 2);
    v |= __shfl_xor(v, 4);
    if ((t & 7) == 0) brow[it * 32 + (t >> 3)] = v;
    float e, p0, p1, p2, p3;
    e = e1i + ev.x; e = e > 0.f ? e : LRELU_ALPHA * e; p0 = (a4.x > 0) ? __expf(e) : 0.f;
    e = e1i + ev.y; e = e > 0.f ? e : LRELU_ALPHA * e; p1 = (a4.y > 0) ? __expf(e) : 0.f;
    e = e1i + ev.z; e = e > 0.f ? e : LRELU_ALPHA * e; p2 = (a4.z > 0) ? __expf(e) : 0.f;
    e = e1i + ev.w; e = e > 0.f ? e : LRELU_ALPHA * e; p3 = (a4.w > 0) ? __expf(e) : 0.f;
    vv[it] = make_float4(p0, p1, p2, p3);
    s += (p0 + p1) + (p2 + p3);
  }
#pragma unroll
  for (int off = 32; off; off >>= 1) s += __shfl_xor(s, off);
  if ((t & 63) == 0) red[t >> 6] = s;
  __syncthreads();
  s = red[0] + red[1] + red[2] + red[3];
  float inv = 1.f / s;
  float4* orow = (float4*)(att + (size_t)i * 8192);
  unsigned short* obrow = attb + (size_t)i * 8192;
#pragma unroll
  for (int it = 0; it < 8; ++it) {
    int j4 = t + it * 256;
    float4 p = vv[it];
    p.x *= inv; p.y *= inv; p.z *= inv; p.w *= inv;
    orow[j4] = p;
    u16x4 b;
    b[0] = f2bf(p.x); b[1] = f2bf(p.y); b[2] = f2bf(p.z); b[3] = f2bf(p.w);
    *(u16x4*)(obrow + j4 * 4) = b;
  }
}

// ---------------- layer-2 masked softmax (bits mask), fp32 out only ----------------
__global__ __launch_bounds__(256) void att_softmax2_k(
    const unsigned* __restrict__ bits, const float* __restrict__ e1,
    const float* __restrict__ e2, float* __restrict__ att)
{
  __shared__ unsigned bw[256];
  __shared__ float red[4];
  int i = blockIdx.x, t = threadIdx.x;
  bw[t] = bits[(size_t)i * 256 + t];
  float e1i = e1[i];
  __syncthreads();
  float4 vv[8];
  float s = 0.f;
#pragma unroll
  for (int it = 0; it < 8; ++it) {
    int j4 = t + it * 256;
    float4 ev = *(const float4*)(e2 + j4 * 4);
    unsigned wb = bw[j4 >> 3];
    int b0 = (j4 & 7) * 4;
    float e, p0, p1, p2, p3;
    e = e1i + ev.x; e = e > 0.f ? e : LRELU_ALPHA * e; p0 = ((wb >> (b0 + 0)) & 1) ? __expf(e) : 0.f;
    e = e1i + ev.y; e = e > 0.f ? e : LRELU_ALPHA * e; p1 = ((wb >> (b0 + 1)) & 1) ? __expf(e) : 0.f;
    e = e1i + ev.z; e = e > 0.f ? e : LRELU_ALPHA * e; p2 = ((wb >> (b0 + 2)) & 1) ? __expf(e) : 0.f;
    e = e1i + ev.w; e = e > 0.f ? e : LRELU_ALPHA * e; p3 = ((wb >> (b0 + 3)) & 1) ? __expf(e) : 0.f;
    vv[it] = make_float4(p0, p1, p2, p3);
    s += (p0 + p1) + (p2 + p3);
  }
#pragma unroll
  for (int off = 32; off; off >>= 1) s += __shfl_xor(s, off);
  if ((t & 63) == 0) red[t >> 6] = s;
  __syncthreads();
  s = red[0] + red[1] + red[2] + red[3];
  float inv = 1.f / s;
  float4* orow = (float4*)(att + (size_t)i * 8192);
#pragma unroll
  for (int it = 0; it < 8; ++it) {
    float4 p = vv[it];
    p.x *= inv; p.y *= inv; p.z *= inv; p.w *= inv;
    orow[t + it * 256] = p;
  }
}

// ---------------- MFMA bf16 GEMM (bf16 A, layer 1): part[z] = att1b @ bt1^T ----------------
// global_load_lds staging (R15-verified): linear LDS dest, per-lane global
// source pre-swizzled (seg ^= row&7) == XOR layout the fragment reads expect.
__global__ __launch_bounds__(256) void gemm_bfA_k(
    const unsigned short* __restrict__ A,    // att1b [8192][8192] bf16
    const unsigned short* __restrict__ BT,   // bt1 [256][8192] bf16
    float* __restrict__ part)                // [4][8192][256]
{
  constexpr int BM = 64, BN = 64, BK = 64;
  __shared__ __align__(16) unsigned short As[BM * 64];   // row stride 128 B
  __shared__ __align__(16) unsigned short Bs[BN * 64];
  int t = threadIdx.x;
  int row0 = blockIdx.x * BM;
  int col0 = blockIdx.y * BN;
  int z = blockIdx.z;
  int kt0 = z * 32;
  int w = t >> 6, l = t & 63;
  int wm = w >> 1, wn = w & 1;

  f32x4 acc[2][2] = {};

  int ra0 = 16 * w + (l >> 3);
  int ra1 = ra0 + 8;
  int sseg = ((l & 7) ^ (ra0 & 7)) * 8;      // (ra1&7)==(ra0&7)
  const unsigned short* gA0 = A + (size_t)(row0 + ra0) * 8192 + kt0 * BK + sseg;
  const unsigned short* gA1 = A + (size_t)(row0 + ra1) * 8192 + kt0 * BK + sseg;
  const unsigned short* gB0 = BT + (size_t)(col0 + ra0) * 8192 + kt0 * BK + sseg;
  const unsigned short* gB1 = BT + (size_t)(col0 + ra1) * 8192 + kt0 * BK + sseg;
  unsigned short* lA0 = As + (16 * w) * 64;        // wave-uniform chunk bases
  unsigned short* lA1 = As + (16 * w + 8) * 64;
  unsigned short* lB0 = Bs + (16 * w) * 64;
  unsigned short* lB1 = Bs + (16 * w + 8) * 64;

  for (int kt = 0; kt < 32; ++kt) {
    __syncthreads();
    gload16(gA0 + kt * BK, lA0);
    gload16(gA1 + kt * BK, lA1);
    gload16(gB0 + kt * BK, lB0);
    gload16(gB1 + kt * BK, lB1);
    __syncthreads();   // compiler drains vmcnt before barrier -> LDS valid
#pragma unroll
    for (int kk = 0; kk < BK; kk += 32) {
      bf16x8 af[2], bfr[2];
      int kb = (kk + (l >> 4) * 8) * 2;
#pragma unroll
      for (int fm = 0; fm < 2; ++fm) {
        int r = wm * 32 + fm * 16 + (l & 15);
        af[fm] = *(const bf16x8*)((const char*)As + ((r * 128 + kb) ^ ((r & 7) << 4)));
      }
#pragma unroll
      for (int fn = 0; fn < 2; ++fn) {
        int c = wn * 32 + fn * 16 + (l & 15);
        bfr[fn] = *(const bf16x8*)((const char*)Bs + ((c * 128 + kb) ^ ((c & 7) << 4)));
      }
#pragma unroll
      for (int fm = 0; fm < 2; ++fm)
#pragma unroll
        for (int fn = 0; fn < 2; ++fn)
          acc[fm][fn] = __builtin_amdgcn_mfma_f32_16x16x32_bf16(af[fm], bfr[fn], acc[fm][fn], 0, 0, 0);
    }
  }
#pragma unroll
  for (int fm = 0; fm < 2; ++fm) {
#pragma unroll
    for (int fn = 0; fn < 2; ++fn) {
#pragma unroll
      for (int r = 0; r < 4; ++r) {
        int grow = row0 + wm * 32 + fm * 16 + (l >> 4) * 4 + r;
        int gcol = col0 + wn * 32 + fn * 16 + (l & 15);
        part[((size_t)z * 8192 + grow) * 256 + gcol] = acc[fm][fn][r];
      }
    }
  }
}

// ---------------- fused layer boundary: part1 -> h1 (ELU) -> wh2 -> bt2 + e1b/e2b ----------------
__global__ __launch_bounds__(256) void epilogue2_k(
    const float* __restrict__ part, const float* __restrict__ W2,
    const float* __restrict__ a2, float* __restrict__ h1,
    unsigned short* __restrict__ bt2, float* __restrict__ e1b,
    float* __restrict__ e2b)
{
  __shared__ float w2s[256][17];
  __shared__ float h1s[4096];
  int t = threadIdx.x;
  int row0 = blockIdx.x * 16;
  { // load W2 [256][16]
    const float4* src = (const float4*)(W2 + t * 16);
    float4 v0 = src[0], v1 = src[1], v2 = src[2], v3 = src[3];
    float* d = &w2s[t][0];
    d[0]=v0.x; d[1]=v0.y; d[2]=v0.z; d[3]=v0.w;
    d[4]=v1.x; d[5]=v1.y; d[6]=v1.z; d[7]=v1.w;
    d[8]=v2.x; d[9]=v2.y; d[10]=v2.z; d[11]=v2.w;
    d[12]=v3.x; d[13]=v3.y; d[14]=v3.z; d[15]=v3.w;
  }
  size_t base = (size_t)row0 * 256;
#pragma unroll
  for (int it = 0; it < 16; ++it) {
    int e = t + it * 256;
    float s = (part[base + e] + part[2097152 + base + e])
            + (part[2 * 2097152 + base + e] + part[3 * 2097152 + base + e]);
    float h = s > 0.f ? s : expm1f(s);
    h1[base + e] = h;
    h1s[e] = h;
  }
  __syncthreads();
  int r = t >> 4, c = t & 15;
  const float* hrow = &h1s[r * 256];
  float acc = 0.f;
#pragma unroll 8
  for (int k = 0; k < 256; ++k)
    acc = fmaf(hrow[k], w2s[k][c], acc);
  bt2[(size_t)c * 8192 + row0 + r] = f2bf(acc);
  float v1 = acc * a2[c];
  float v2 = acc * a2[16 + c];
#pragma unroll
  for (int off = 8; off; off >>= 1) {
    v1 += __shfl_xor(v1, off);
    v2 += __shfl_xor(v2, off);
  }
  if (c == 0) { e1b[row0 + r] = v1; e2b[row0 + r] = v2; }
}

// ---------------- MFMA bf16 GEMM (layer 2, fp32 A): part2[z] = att2 @ bt2^T ----------------
__global__ __launch_bounds__(256) void gemm_mfma2_k(
    const float* __restrict__ A, const unsigned short* __restrict__ BT,
    float* __restrict__ part)
{
  constexpr int BM = 64, BN = 16, BK = 64;
  __shared__ __align__(16) char As[BM * 128];
  __shared__ __align__(16) char Bs[BN * 128];
  int t = threadIdx.x;
  int row0 = blockIdx.x * BM;
  int z = blockIdx.z;
  int kt0 = z * 32, kt1 = kt0 + 32;
  int w = t >> 6, l = t & 63;

  f32x4 acc = {};

  int ar = t >> 2, aseg = t & 3;
  int swzA = (ar & 7) << 4;

  for (int kt = kt0; kt < kt1; ++kt) {
    __syncthreads();
    {
      const float4* src = (const float4*)(A + (size_t)(row0 + ar) * 8192 + kt * BK + aseg * 16);
      float4 v0 = src[0], v1 = src[1], v2 = src[2], v3 = src[3];
      u16x8 c0, c1;
      c0[0]=f2bf(v0.x); c0[1]=f2bf(v0.y); c0[2]=f2bf(v0.z); c0[3]=f2bf(v0.w);
      c0[4]=f2bf(v1.x); c0[5]=f2bf(v1.y); c0[6]=f2bf(v1.z); c0[7]=f2bf(v1.w);
      c1[0]=f2bf(v2.x); c1[1]=f2bf(v2.y); c1[2]=f2bf(v2.z); c1[3]=f2bf(v2.w);
      c1[4]=f2bf(v3.x); c1[5]=f2bf(v3.y); c1[6]=f2bf(v3.z); c1[7]=f2bf(v3.w);
      int base = ar * 128 + aseg * 32;
      *(u16x8*)(As + ((base) ^ swzA)) = c0;
      *(u16x8*)(As + ((base + 16) ^ swzA)) = c1;
    }
    {
      int br = t >> 4, seg = t & 15;
      const u16x4* src = (const u16x4*)(BT + (size_t)br * 8192 + kt * BK + seg * 4);
      u16x4 b0 = src[0];
      int base = br * 128 + seg * 8;
      int swz = (br & 7) << 4;
      *(u16x4*)(Bs + (base ^ swz)) = b0;
    }
    __syncthreads();
#pragma unroll
    for (int kk = 0; kk < BK; kk += 32) {
      int kb = (kk + (l >> 4) * 8) * 2;
      int r = w * 16 + (l & 15);
      bf16x8 af = *(const bf16x8*)(As + ((r * 128 + kb) ^ ((r & 7) << 4)));
      int c = l & 15;
      bf16x8 bf = *(const bf16x8*)(Bs + ((c * 128 + kb) ^ ((c & 7) << 4)));
      acc = __builtin_amdgcn_mfma_f32_16x16x32_bf16(af, bf, acc, 0, 0, 0);
    }
  }
#pragma unroll
  for (int r = 0; r < 4; ++r) {
    int grow = row0 + w * 16 + (l >> 4) * 4 + r;
    int gcol = l & 15;
    part[((size_t)z * 8192 + grow) * 16 + gcol] = acc[r];
  }
}

// ---------------- split-K reduce + sigmoid (4 partials) ----------------
__global__ void reduce_sig_k(const float* __restrict__ part, float* __restrict__ out, int total)
{
  int i = blockIdx.x * 256 + threadIdx.x;
  if (i < total) {
    float s = part[i] + part[total + i] + part[2 * (size_t)total + i] + part[3 * (size_t)total + i];
    out[i] = 1.f / (1.f + __expf(-s));
  }
}

extern "C" void kernel_launch(void* const* d_in, const int* in_sizes, int n_in,
                              void* d_out, int out_size, void* d_ws, size_t ws_size,
                              hipStream_t stream)
{
  const float* x   = (const float*)d_in[0];
  const int*   adj = (const int*)d_in[1];
  const float* W1  = (const float*)d_in[2];
  const float* a1  = (const float*)d_in[3];
  const float* W2  = (const float*)d_in[4];
  const float* a2  = (const float*)d_in[5];

  float* out  = (float*)d_out;                 // [8192*16]
  float* h1   = out + 131072;                  // [8192*256]
  float* att1 = h1 + 2097152;                  // [8192*8192]
  float* att2 = att1 + 67108864;               // [8192*8192]

  float* ws = (float*)d_ws;
  float* wh1 = ws;                                            // 2097152 f
  unsigned short* bt1 = (unsigned short*)(wh1 + 2097152);     // 2097152 u16
  float* e1a = wh1 + 2097152 + 1048576;
  float* e2a = e1a + 8192;
  unsigned short* bt2 = (unsigned short*)(e2a + 8192);        // 131072 u16
  float* e1b = (float*)(bt2 + 131072);
  float* e2b = e1b + 8192;
  float* part2 = e2b + 8192;                                  // 4*131072 f
  unsigned* bits = (unsigned*)(part2 + 524288);               // 2097152 u32
  float* part1 = (float*)(bits + 2097152);                    // 4*2097152 f
  unsigned short* att1b = (unsigned short*)(part1 + 8388608); // 67108864 u16
  unsigned short* w1t = att1b + 67108864;                     // 131072 u16

  // ---- layer 1 ----
  transpose_bf16_k<<<dim3(8, 16), dim3(32, 8), 0, stream>>>(W1, w1t, 512, 256);
  gemm_wh1_k<<<dim3(128, 4), 256, 0, stream>>>(x, w1t, wh1);
  calc_e_k<<<2048, 256, 0, stream>>>(wh1, a1, e1a, e2a, 256);
  transpose_bf16_k<<<dim3(8, 256), dim3(32, 8), 0, stream>>>(wh1, bt1, 8192, 256);
  att_softmax1_k<<<8192, 256, 0, stream>>>(adj, e1a, e2a, att1, att1b, bits);
  gemm_bfA_k<<<dim3(128, 4, 4), 256, 0, stream>>>(att1b, bt1, part1);

  // ---- layer boundary (fused): h1, bt2, e1b/e2b ----
  epilogue2_k<<<512, 256, 0, stream>>>(part1, W2, a2, h1, bt2, e1b, e2b);

  // ---- layer 2 ----
  att_softmax2_k<<<8192, 256, 0, stream>>>(bits, e1b, e2b, att2);
  gemm_mfma2_k<<<dim3(128, 1, 4), 256, 0, stream>>>(att2, bt2, part2);
  reduce_sig_k<<<512, 256, 0, stream>>>(part2, out, 131072);
}

// Round 17
// 377.416 us; speedup vs baseline: 1.2133x; 1.0123x over previous
//
#include <hip/hip_runtime.h>
#include <hip/hip_bf16.h>

#define LRELU_ALPHA 0.2f

typedef __attribute__((ext_vector_type(8))) __bf16 bf16x8;
typedef __attribute__((ext_vector_type(4))) float f32x4;
typedef __attribute__((ext_vector_type(8))) unsigned short u16x8;
typedef __attribute__((ext_vector_type(4))) unsigned short u16x4;

__device__ __forceinline__ unsigned short f2bf(float f) {
  unsigned int u = __float_as_uint(f);
  u += 0x7fffu + ((u >> 16) & 1u);   // round-to-nearest-even
  return (unsigned short)(u >> 16);
}

__device__ __forceinline__ void gload16(const void* g, void* l) {
  __builtin_amdgcn_global_load_lds(
      (const __attribute__((address_space(1))) void*)g,
      (__attribute__((address_space(3))) void*)l, 16, 0, 0);
}

// ---------------- transpose + fp32->bf16 (W1 only): out[c][r] = bf16(in[r][c]) ----------------
__global__ void transpose_bf16_k(const float* __restrict__ in, unsigned short* __restrict__ out,
                                 int R, int Cc)
{
  __shared__ float tile[32][33];
  int tx = threadIdx.x, ty = threadIdx.y;
  int c0 = blockIdx.x * 32, r0 = blockIdx.y * 32;
  int c = c0 + tx;
  if (c < Cc) {
    for (int i = ty; i < 32; i += 8)
      tile[i][tx] = in[(size_t)(r0 + i) * Cc + c];
  }
  __syncthreads();
  int r = r0 + tx;
  for (int i = ty; i < 32; i += 8) {
    int cc = c0 + i;
    if (cc < Cc)
      out[(size_t)cc * R + r] = f2bf(tile[tx][i]);
  }
}

// ---------------- MFMA GEMM: wh1 = x @ W1 (via w1t bf16), dual-writes bt1 ----------------
// BM=BN=64, K=512 (8 kt), 4 waves 2x2, fp32-A staged with f2bf (R9-proven body).
// Epilogue writes wh1 fp32 AND bt1[c][r] bf16 (replaces the 8MB transpose pass).
__global__ __launch_bounds__(256) void gemm_wh1_k(
    const float* __restrict__ A,             // x [8192][512]
    const unsigned short* __restrict__ BT,   // w1t [256][512] bf16
    float* __restrict__ C,                   // wh1 [8192][256]
    unsigned short* __restrict__ bt1)        // [256][8192] bf16
{
  constexpr int BK = 64;
  __shared__ __align__(16) char As[64 * 128];
  __shared__ __align__(16) char Bs[64 * 128];
  int t = threadIdx.x;
  int row0 = blockIdx.x * 64;
  int col0 = blockIdx.y * 64;
  int w = t >> 6, l = t & 63;
  int wm = w >> 1, wn = w & 1;

  f32x4 acc[2][2] = {};

  int ar = t >> 2, aseg = t & 3;
  int swzA = (ar & 7) << 4;

  for (int kt = 0; kt < 8; ++kt) {
    __syncthreads();
    { // stage A (fp32 -> bf16, swizzled)
      const float4* src = (const float4*)(A + (size_t)(row0 + ar) * 512 + kt * BK + aseg * 16);
      float4 v0 = src[0], v1 = src[1], v2 = src[2], v3 = src[3];
      u16x8 c0, c1;
      c0[0]=f2bf(v0.x); c0[1]=f2bf(v0.y); c0[2]=f2bf(v0.z); c0[3]=f2bf(v0.w);
      c0[4]=f2bf(v1.x); c0[5]=f2bf(v1.y); c0[6]=f2bf(v1.z); c0[7]=f2bf(v1.w);
      c1[0]=f2bf(v2.x); c1[1]=f2bf(v2.y); c1[2]=f2bf(v2.z); c1[3]=f2bf(v2.w);
      c1[4]=f2bf(v3.x); c1[5]=f2bf(v3.y); c1[6]=f2bf(v3.z); c1[7]=f2bf(v3.w);
      int base = ar * 128 + aseg * 32;
      *(u16x8*)(As + ((base) ^ swzA)) = c0;
      *(u16x8*)(As + ((base + 16) ^ swzA)) = c1;
    }
    { // stage B
      int br = t >> 2, seg = t & 3;
      const u16x8* src = (const u16x8*)(BT + (size_t)(col0 + br) * 512 + kt * BK + seg * 16);
      u16x8 b0 = src[0], b1 = src[1];
      int base = br * 128 + seg * 32;
      int swz = (br & 7) << 4;
      *(u16x8*)(Bs + ((base) ^ swz)) = b0;
      *(u16x8*)(Bs + ((base + 16) ^ swz)) = b1;
    }
    __syncthreads();
#pragma unroll
    for (int kk = 0; kk < BK; kk += 32) {
      bf16x8 af[2], bfr[2];
      int kb = (kk + (l >> 4) * 8) * 2;
#pragma unroll
      for (int fm = 0; fm < 2; ++fm) {
        int r = wm * 32 + fm * 16 + (l & 15);
        af[fm] = *(const bf16x8*)(As + ((r * 128 + kb) ^ ((r & 7) << 4)));
      }
#pragma unroll
      for (int fn = 0; fn < 2; ++fn) {
        int c = wn * 32 + fn * 16 + (l & 15);
        bfr[fn] = *(const bf16x8*)(Bs + ((c * 128 + kb) ^ ((c & 7) << 4)));
      }
#pragma unroll
      for (int fm = 0; fm < 2; ++fm)
#pragma unroll
        for (int fn = 0; fn < 2; ++fn)
          acc[fm][fn] = __builtin_amdgcn_mfma_f32_16x16x32_bf16(af[fm], bfr[fn], acc[fm][fn], 0, 0, 0);
    }
  }
  // epilogue: wh1 fp32 + bt1 bf16 transposed (4 consecutive rows/lane = 8B store)
#pragma unroll
  for (int fm = 0; fm < 2; ++fm) {
#pragma unroll
    for (int fn = 0; fn < 2; ++fn) {
      int grow0 = row0 + wm * 32 + fm * 16 + (l >> 4) * 4;
      int gcol = col0 + wn * 32 + fn * 16 + (l & 15);
      u16x4 bt;
#pragma unroll
      for (int r = 0; r < 4; ++r) {
        float v = acc[fm][fn][r];
        C[(size_t)(grow0 + r) * 256 + gcol] = v;
        bt[r] = f2bf(v);
      }
      *(u16x4*)(bt1 + (size_t)gcol * 8192 + grow0) = bt;
    }
  }
}

// ---------------- e1/e2 vectors (layer 1): wave per row ----------------
__global__ __launch_bounds__(256) void calc_e_k(
    const float* __restrict__ Wh, const float* __restrict__ a,
    float* __restrict__ e1, float* __restrict__ e2, int F)
{
  int row = blockIdx.x * 4 + (threadIdx.x >> 6);
  int l = threadIdx.x & 63;
  const float* r = Wh + (size_t)row * F;
  float s1 = 0.f, s2 = 0.f;
  for (int f = l; f < F; f += 64) {
    float v = r[f];
    s1 += v * a[f];
    s2 += v * a[F + f];
  }
#pragma unroll
  for (int off = 32; off; off >>= 1) {
    s1 += __shfl_down(s1, off);
    s2 += __shfl_down(s2, off);
  }
  if (l == 0) { e1[row] = s1; e2[row] = s2; }
}

// ---------------- layer-1 masked softmax + inline adj bit-pack + bf16 dual write ----------------
__global__ __launch_bounds__(256) void att_softmax1_k(
    const int* __restrict__ adj, const float* __restrict__ e1,
    const float* __restrict__ e2, float* __restrict__ att,
    unsigned short* __restrict__ attb, unsigned* __restrict__ bits)
{
  __shared__ float red[4];
  int i = blockIdx.x, t = threadIdx.x;
  const int4* arow = (const int4*)(adj + (size_t)i * 8192);
  unsigned* brow = bits + (size_t)i * 256;
  float e1i = e1[i];
  float4 vv[8];
  float s = 0.f;
#pragma unroll
  for (int it = 0; it < 8; ++it) {
    int j4 = t + it * 256;               // int4/float4 index
    int4 a4 = arow[j4];
    float4 ev = *(const float4*)(e2 + j4 * 4);
    unsigned n = (unsigned)(a4.x > 0) | ((unsigned)(a4.y > 0) << 1)
               | ((unsigned)(a4.z > 0) << 2) | ((unsigned)(a4.w > 0) << 3);
    unsigned v = n << ((t & 7) * 4);
    v |= __shfl_xor(v, 1);
    v |= __shfl_xor(v, 2);
    v |= __shfl_xor(v, 4);
    if ((t & 7) == 0) brow[it * 32 + (t >> 3)] = v;
    float e, p0, p1, p2, p3;
    e = e1i + ev.x; e = e > 0.f ? e : LRELU_ALPHA * e; p0 = (a4.x > 0) ? __expf(e) : 0.f;
    e = e1i + ev.y; e = e > 0.f ? e : LRELU_ALPHA * e; p1 = (a4.y > 0) ? __expf(e) : 0.f;
    e = e1i + ev.z; e = e > 0.f ? e : LRELU_ALPHA * e; p2 = (a4.z > 0) ? __expf(e) : 0.f;
    e = e1i + ev.w; e = e > 0.f ? e : LRELU_ALPHA * e; p3 = (a4.w > 0) ? __expf(e) : 0.f;
    vv[it] = make_float4(p0, p1, p2, p3);
    s += (p0 + p1) + (p2 + p3);
  }
#pragma unroll
  for (int off = 32; off; off >>= 1) s += __shfl_xor(s, off);
  if ((t & 63) == 0) red[t >> 6] = s;
  __syncthreads();
  s = red[0] + red[1] + red[2] + red[3];
  float inv = 1.f / s;
  float4* orow = (float4*)(att + (size_t)i * 8192);
  unsigned short* obrow = attb + (size_t)i * 8192;
#pragma unroll
  for (int it = 0; it < 8; ++it) {
    int j4 = t + it * 256;
    float4 p = vv[it];
    p.x *= inv; p.y *= inv; p.z *= inv; p.w *= inv;
    orow[j4] = p;
    u16x4 b;
    b[0] = f2bf(p.x); b[1] = f2bf(p.y); b[2] = f2bf(p.z); b[3] = f2bf(p.w);
    *(u16x4*)(obrow + j4 * 4) = b;
  }
}

// ---------------- layer-2 masked softmax (bits mask), fp32 out only ----------------
__global__ __launch_bounds__(256) void att_softmax2_k(
    const unsigned* __restrict__ bits, const float* __restrict__ e1,
    const float* __restrict__ e2, float* __restrict__ att)
{
  __shared__ unsigned bw[256];
  __shared__ float red[4];
  int i = blockIdx.x, t = threadIdx.x;
  bw[t] = bits[(size_t)i * 256 + t];
  float e1i = e1[i];
  __syncthreads();
  float4 vv[8];
  float s = 0.f;
#pragma unroll
  for (int it = 0; it < 8; ++it) {
    int j4 = t + it * 256;
    float4 ev = *(const float4*)(e2 + j4 * 4);
    unsigned wb = bw[j4 >> 3];
    int b0 = (j4 & 7) * 4;
    float e, p0, p1, p2, p3;
    e = e1i + ev.x; e = e > 0.f ? e : LRELU_ALPHA * e; p0 = ((wb >> (b0 + 0)) & 1) ? __expf(e) : 0.f;
    e = e1i + ev.y; e = e > 0.f ? e : LRELU_ALPHA * e; p1 = ((wb >> (b0 + 1)) & 1) ? __expf(e) : 0.f;
    e = e1i + ev.z; e = e > 0.f ? e : LRELU_ALPHA * e; p2 = ((wb >> (b0 + 2)) & 1) ? __expf(e) : 0.f;
    e = e1i + ev.w; e = e > 0.f ? e : LRELU_ALPHA * e; p3 = ((wb >> (b0 + 3)) & 1) ? __expf(e) : 0.f;
    vv[it] = make_float4(p0, p1, p2, p3);
    s += (p0 + p1) + (p2 + p3);
  }
#pragma unroll
  for (int off = 32; off; off >>= 1) s += __shfl_xor(s, off);
  if ((t & 63) == 0) red[t >> 6] = s;
  __syncthreads();
  s = red[0] + red[1] + red[2] + red[3];
  float inv = 1.f / s;
  float4* orow = (float4*)(att + (size_t)i * 8192);
#pragma unroll
  for (int it = 0; it < 8; ++it) {
    float4 p = vv[it];
    p.x *= inv; p.y *= inv; p.z *= inv; p.w *= inv;
    orow[t + it * 256] = p;
  }
}

// ---------------- MFMA bf16 GEMM (bf16 A, layer 1): part[z] = att1b @ bt1^T ----------------
// global_load_lds staging (R15-verified): linear LDS dest, per-lane global
// source pre-swizzled (seg ^= row&7) == XOR layout the fragment reads expect.
__global__ __launch_bounds__(256) void gemm_bfA_k(
    const unsigned short* __restrict__ A,    // att1b [8192][8192] bf16
    const unsigned short* __restrict__ BT,   // bt1 [256][8192] bf16
    float* __restrict__ part)                // [4][8192][256]
{
  constexpr int BM = 64, BN = 64, BK = 64;
  __shared__ __align__(16) unsigned short As[BM * 64];   // row stride 128 B
  __shared__ __align__(16) unsigned short Bs[BN * 64];
  int t = threadIdx.x;
  int row0 = blockIdx.x * BM;
  int col0 = blockIdx.y * BN;
  int z = blockIdx.z;
  int kt0 = z * 32;
  int w = t >> 6, l = t & 63;
  int wm = w >> 1, wn = w & 1;

  f32x4 acc[2][2] = {};

  int ra0 = 16 * w + (l >> 3);
  int ra1 = ra0 + 8;
  int sseg = ((l & 7) ^ (ra0 & 7)) * 8;      // (ra1&7)==(ra0&7)
  const unsigned short* gA0 = A + (size_t)(row0 + ra0) * 8192 + kt0 * BK + sseg;
  const unsigned short* gA1 = A + (size_t)(row0 + ra1) * 8192 + kt0 * BK + sseg;
  const unsigned short* gB0 = BT + (size_t)(col0 + ra0) * 8192 + kt0 * BK + sseg;
  const unsigned short* gB1 = BT + (size_t)(col0 + ra1) * 8192 + kt0 * BK + sseg;
  unsigned short* lA0 = As + (16 * w) * 64;        // wave-uniform chunk bases
  unsigned short* lA1 = As + (16 * w + 8) * 64;
  unsigned short* lB0 = Bs + (16 * w) * 64;
  unsigned short* lB1 = Bs + (16 * w + 8) * 64;

  for (int kt = 0; kt < 32; ++kt) {
    __syncthreads();
    gload16(gA0 + kt * BK, lA0);
    gload16(gA1 + kt * BK, lA1);
    gload16(gB0 + kt * BK, lB0);
    gload16(gB1 + kt * BK, lB1);
    __syncthreads();   // compiler drains vmcnt before barrier -> LDS valid
#pragma unroll
    for (int kk = 0; kk < BK; kk += 32) {
      bf16x8 af[2], bfr[2];
      int kb = (kk + (l >> 4) * 8) * 2;
#pragma unroll
      for (int fm = 0; fm < 2; ++fm) {
        int r = wm * 32 + fm * 16 + (l & 15);
        af[fm] = *(const bf16x8*)((const char*)As + ((r * 128 + kb) ^ ((r & 7) << 4)));
      }
#pragma unroll
      for (int fn = 0; fn < 2; ++fn) {
        int c = wn * 32 + fn * 16 + (l & 15);
        bfr[fn] = *(const bf16x8*)((const char*)Bs + ((c * 128 + kb) ^ ((c & 7) << 4)));
      }
#pragma unroll
      for (int fm = 0; fm < 2; ++fm)
#pragma unroll
        for (int fn = 0; fn < 2; ++fn)
          acc[fm][fn] = __builtin_amdgcn_mfma_f32_16x16x32_bf16(af[fm], bfr[fn], acc[fm][fn], 0, 0, 0);
    }
  }
#pragma unroll
  for (int fm = 0; fm < 2; ++fm) {
#pragma unroll
    for (int fn = 0; fn < 2; ++fn) {
#pragma unroll
      for (int r = 0; r < 4; ++r) {
        int grow = row0 + wm * 32 + fm * 16 + (l >> 4) * 4 + r;
        int gcol = col0 + wn * 32 + fn * 16 + (l & 15);
        part[((size_t)z * 8192 + grow) * 256 + gcol] = acc[fm][fn][r];
      }
    }
  }
}

// ---------------- fused layer boundary: part1 -> h1 (ELU) -> wh2 -> bt2 + e1b/e2b ----------------
__global__ __launch_bounds__(256) void epilogue2_k(
    const float* __restrict__ part, const float* __restrict__ W2,
    const float* __restrict__ a2, float* __restrict__ h1,
    unsigned short* __restrict__ bt2, float* __restrict__ e1b,
    float* __restrict__ e2b)
{
  __shared__ float w2s[256][17];
  __shared__ float h1s[4096];
  int t = threadIdx.x;
  int row0 = blockIdx.x * 16;
  { // load W2 [256][16]
    const float4* src = (const float4*)(W2 + t * 16);
    float4 v0 = src[0], v1 = src[1], v2 = src[2], v3 = src[3];
    float* d = &w2s[t][0];
    d[0]=v0.x; d[1]=v0.y; d[2]=v0.z; d[3]=v0.w;
    d[4]=v1.x; d[5]=v1.y; d[6]=v1.z; d[7]=v1.w;
    d[8]=v2.x; d[9]=v2.y; d[10]=v2.z; d[11]=v2.w;
    d[12]=v3.x; d[13]=v3.y; d[14]=v3.z; d[15]=v3.w;
  }
  size_t base = (size_t)row0 * 256;
#pragma unroll
  for (int it = 0; it < 16; ++it) {
    int e = t + it * 256;
    float s = (part[base + e] + part[2097152 + base + e])
            + (part[2 * 2097152 + base + e] + part[3 * 2097152 + base + e]);
    float h = s > 0.f ? s : expm1f(s);
    h1[base + e] = h;
    h1s[e] = h;
  }
  __syncthreads();
  int r = t >> 4, c = t & 15;
  const float* hrow = &h1s[r * 256];
  float acc = 0.f;
#pragma unroll 8
  for (int k = 0; k < 256; ++k)
    acc = fmaf(hrow[k], w2s[k][c], acc);
  bt2[(size_t)c * 8192 + row0 + r] = f2bf(acc);
  float v1 = acc * a2[c];
  float v2 = acc * a2[16 + c];
#pragma unroll
  for (int off = 8; off; off >>= 1) {
    v1 += __shfl_xor(v1, off);
    v2 += __shfl_xor(v2, off);
  }
  if (c == 0) { e1b[row0 + r] = v1; e2b[row0 + r] = v2; }
}

// ---------------- MFMA bf16 GEMM (layer 2, fp32 A): part2[z] = att2 @ bt2^T ----------------
__global__ __launch_bounds__(256) void gemm_mfma2_k(
    const float* __restrict__ A, const unsigned short* __restrict__ BT,
    float* __restrict__ part)
{
  constexpr int BM = 64, BN = 16, BK = 64;
  __shared__ __align__(16) char As[BM * 128];
  __shared__ __align__(16) char Bs[BN * 128];
  int t = threadIdx.x;
  int row0 = blockIdx.x * BM;
  int z = blockIdx.z;
  int kt0 = z * 32, kt1 = kt0 + 32;
  int w = t >> 6, l = t & 63;

  f32x4 acc = {};

  int ar = t >> 2, aseg = t & 3;
  int swzA = (ar & 7) << 4;

  for (int kt = kt0; kt < kt1; ++kt) {
    __syncthreads();
    {
      const float4* src = (const float4*)(A + (size_t)(row0 + ar) * 8192 + kt * BK + aseg * 16);
      float4 v0 = src[0], v1 = src[1], v2 = src[2], v3 = src[3];
      u16x8 c0, c1;
      c0[0]=f2bf(v0.x); c0[1]=f2bf(v0.y); c0[2]=f2bf(v0.z); c0[3]=f2bf(v0.w);
      c0[4]=f2bf(v1.x); c0[5]=f2bf(v1.y); c0[6]=f2bf(v1.z); c0[7]=f2bf(v1.w);
      c1[0]=f2bf(v2.x); c1[1]=f2bf(v2.y); c1[2]=f2bf(v2.z); c1[3]=f2bf(v2.w);
      c1[4]=f2bf(v3.x); c1[5]=f2bf(v3.y); c1[6]=f2bf(v3.z); c1[7]=f2bf(v3.w);
      int base = ar * 128 + aseg * 32;
      *(u16x8*)(As + ((base) ^ swzA)) = c0;
      *(u16x8*)(As + ((base + 16) ^ swzA)) = c1;
    }
    {
      int br = t >> 4, seg = t & 15;
      const u16x4* src = (const u16x4*)(BT + (size_t)br * 8192 + kt * BK + seg * 4);
      u16x4 b0 = src[0];
      int base = br * 128 + seg * 8;
      int swz = (br & 7) << 4;
      *(u16x4*)(Bs + (base ^ swz)) = b0;
    }
    __syncthreads();
#pragma unroll
    for (int kk = 0; kk < BK; kk += 32) {
      int kb = (kk + (l >> 4) * 8) * 2;
      int r = w * 16 + (l & 15);
      bf16x8 af = *(const bf16x8*)(As + ((r * 128 + kb) ^ ((r & 7) << 4)));
      int c = l & 15;
      bf16x8 bf = *(const bf16x8*)(Bs + ((c * 128 + kb) ^ ((c & 7) << 4)));
      acc = __builtin_amdgcn_mfma_f32_16x16x32_bf16(af, bf, acc, 0, 0, 0);
    }
  }
#pragma unroll
  for (int r = 0; r < 4; ++r) {
    int grow = row0 + w * 16 + (l >> 4) * 4 + r;
    int gcol = l & 15;
    part[((size_t)z * 8192 + grow) * 16 + gcol] = acc[r];
  }
}

// ---------------- split-K reduce + sigmoid (4 partials) ----------------
__global__ void reduce_sig_k(const float* __restrict__ part, float* __restrict__ out, int total)
{
  int i = blockIdx.x * 256 + threadIdx.x;
  if (i < total) {
    float s = part[i] + part[total + i] + part[2 * (size_t)total + i] + part[3 * (size_t)total + i];
    out[i] = 1.f / (1.f + __expf(-s));
  }
}

extern "C" void kernel_launch(void* const* d_in, const int* in_sizes, int n_in,
                              void* d_out, int out_size, void* d_ws, size_t ws_size,
                              hipStream_t stream)
{
  const float* x   = (const float*)d_in[0];
  const int*   adj = (const int*)d_in[1];
  const float* W1  = (const float*)d_in[2];
  const float* a1  = (const float*)d_in[3];
  const float* W2  = (const float*)d_in[4];
  const float* a2  = (const float*)d_in[5];

  float* out  = (float*)d_out;                 // [8192*16]
  float* h1   = out + 131072;                  // [8192*256]
  float* att1 = h1 + 2097152;                  // [8192*8192]
  float* att2 = att1 + 67108864;               // [8192*8192]

  float* ws = (float*)d_ws;
  float* wh1 = ws;                                            // 2097152 f
  unsigned short* bt1 = (unsigned short*)(wh1 + 2097152);     // 2097152 u16
  float* e1a = wh1 + 2097152 + 1048576;
  float* e2a = e1a + 8192;
  unsigned short* bt2 = (unsigned short*)(e2a + 8192);        // 131072 u16
  float* e1b = (float*)(bt2 + 131072);
  float* e2b = e1b + 8192;
  float* part2 = e2b + 8192;                                  // 4*131072 f
  unsigned* bits = (unsigned*)(part2 + 524288);               // 2097152 u32
  float* part1 = (float*)(bits + 2097152);                    // 4*2097152 f
  unsigned short* att1b = (unsigned short*)(part1 + 8388608); // 67108864 u16
  unsigned short* w1t = att1b + 67108864;                     // 131072 u16

  // ---- layer 1 ----
  transpose_bf16_k<<<dim3(8, 16), dim3(32, 8), 0, stream>>>(W1, w1t, 512, 256);
  gemm_wh1_k<<<dim3(128, 4), 256, 0, stream>>>(x, w1t, wh1, bt1);
  calc_e_k<<<2048, 256, 0, stream>>>(wh1, a1, e1a, e2a, 256);
  att_softmax1_k<<<8192, 256, 0, stream>>>(adj, e1a, e2a, att1, att1b, bits);
  gemm_bfA_k<<<dim3(128, 4, 4), 256, 0, stream>>>(att1b, bt1, part1);

  // ---- layer boundary (fused): h1, bt2, e1b/e2b ----
  epilogue2_k<<<512, 256, 0, stream>>>(part1, W2, a2, h1, bt2, e1b, e2b);

  // ---- layer 2 ----
  att_softmax2_k<<<8192, 256, 0, stream>>>(bits, e1b, e2b, att2);
  gemm_mfma2_k<<<dim3(128, 1, 4), 256, 0, stream>>>(att2, bt2, part2);
  reduce_sig_k<<<512, 256, 0, stream>>>(part2, out, 131072);
}

// Round 19
// 377.028 us; speedup vs baseline: 1.2146x; 1.0010x over previous
//
#include <hip/hip_runtime.h>
#include <hip/hip_bf16.h>

#define LRELU_ALPHA 0.2f

typedef __attribute__((ext_vector_type(8))) __bf16 bf16x8;
typedef __attribute__((ext_vector_type(4))) float f32x4;
typedef __attribute__((ext_vector_type(8))) unsigned short u16x8;
typedef __attribute__((ext_vector_type(4))) unsigned short u16x4;

__device__ __forceinline__ unsigned short f2bf(float f) {
  unsigned int u = __float_as_uint(f);
  u += 0x7fffu + ((u >> 16) & 1u);   // round-to-nearest-even
  return (unsigned short)(u >> 16);
}

__device__ __forceinline__ void gload16(const void* g, void* l) {
  __builtin_amdgcn_global_load_lds(
      (const __attribute__((address_space(1))) void*)g,
      (__attribute__((address_space(3))) void*)l, 16, 0, 0);
}

// ---------------- transpose + fp32->bf16 (W1 only): out[c][r] = bf16(in[r][c]) ----------------
__global__ void transpose_bf16_k(const float* __restrict__ in, unsigned short* __restrict__ out,
                                 int R, int Cc)
{
  __shared__ float tile[32][33];
  int tx = threadIdx.x, ty = threadIdx.y;
  int c0 = blockIdx.x * 32, r0 = blockIdx.y * 32;
  int c = c0 + tx;
  if (c < Cc) {
    for (int i = ty; i < 32; i += 8)
      tile[i][tx] = in[(size_t)(r0 + i) * Cc + c];
  }
  __syncthreads();
  int r = r0 + tx;
  for (int i = ty; i < 32; i += 8) {
    int cc = c0 + i;
    if (cc < Cc)
      out[(size_t)cc * R + r] = f2bf(tile[tx][i]);
  }
}

// ---------------- MFMA GEMM: wh1 = x @ W1 (via w1t bf16), dual-writes bt1 ----------------
__global__ __launch_bounds__(256) void gemm_wh1_k(
    const float* __restrict__ A,             // x [8192][512]
    const unsigned short* __restrict__ BT,   // w1t [256][512] bf16
    float* __restrict__ C,                   // wh1 [8192][256]
    unsigned short* __restrict__ bt1)        // [256][8192] bf16
{
  constexpr int BK = 64;
  __shared__ __align__(16) char As[64 * 128];
  __shared__ __align__(16) char Bs[64 * 128];
  int t = threadIdx.x;
  int row0 = blockIdx.x * 64;
  int col0 = blockIdx.y * 64;
  int w = t >> 6, l = t & 63;
  int wm = w >> 1, wn = w & 1;

  f32x4 acc[2][2] = {};

  int ar = t >> 2, aseg = t & 3;
  int swzA = (ar & 7) << 4;

  for (int kt = 0; kt < 8; ++kt) {
    __syncthreads();
    { // stage A (fp32 -> bf16, swizzled)
      const float4* src = (const float4*)(A + (size_t)(row0 + ar) * 512 + kt * BK + aseg * 16);
      float4 v0 = src[0], v1 = src[1], v2 = src[2], v3 = src[3];
      u16x8 c0, c1;
      c0[0]=f2bf(v0.x); c0[1]=f2bf(v0.y); c0[2]=f2bf(v0.z); c0[3]=f2bf(v0.w);
      c0[4]=f2bf(v1.x); c0[5]=f2bf(v1.y); c0[6]=f2bf(v1.z); c0[7]=f2bf(v1.w);
      c1[0]=f2bf(v2.x); c1[1]=f2bf(v2.y); c1[2]=f2bf(v2.z); c1[3]=f2bf(v2.w);
      c1[4]=f2bf(v3.x); c1[5]=f2bf(v3.y); c1[6]=f2bf(v3.z); c1[7]=f2bf(v3.w);
      int base = ar * 128 + aseg * 32;
      *(u16x8*)(As + ((base) ^ swzA)) = c0;
      *(u16x8*)(As + ((base + 16) ^ swzA)) = c1;
    }
    { // stage B
      int br = t >> 2, seg = t & 3;
      const u16x8* src = (const u16x8*)(BT + (size_t)(col0 + br) * 512 + kt * BK + seg * 16);
      u16x8 b0 = src[0], b1 = src[1];
      int base = br * 128 + seg * 32;
      int swz = (br & 7) << 4;
      *(u16x8*)(Bs + ((base) ^ swz)) = b0;
      *(u16x8*)(Bs + ((base + 16) ^ swz)) = b1;
    }
    __syncthreads();
#pragma unroll
    for (int kk = 0; kk < BK; kk += 32) {
      bf16x8 af[2], bfr[2];
      int kb = (kk + (l >> 4) * 8) * 2;
#pragma unroll
      for (int fm = 0; fm < 2; ++fm) {
        int r = wm * 32 + fm * 16 + (l & 15);
        af[fm] = *(const bf16x8*)(As + ((r * 128 + kb) ^ ((r & 7) << 4)));
      }
#pragma unroll
      for (int fn = 0; fn < 2; ++fn) {
        int c = wn * 32 + fn * 16 + (l & 15);
        bfr[fn] = *(const bf16x8*)(Bs + ((c * 128 + kb) ^ ((c & 7) << 4)));
      }
#pragma unroll
      for (int fm = 0; fm < 2; ++fm)
#pragma unroll
        for (int fn = 0; fn < 2; ++fn)
          acc[fm][fn] = __builtin_amdgcn_mfma_f32_16x16x32_bf16(af[fm], bfr[fn], acc[fm][fn], 0, 0, 0);
    }
  }
  // epilogue: wh1 fp32 + bt1 bf16 transposed (4 consecutive rows/lane = 8B store)
#pragma unroll
  for (int fm = 0; fm < 2; ++fm) {
#pragma unroll
    for (int fn = 0; fn < 2; ++fn) {
      int grow0 = row0 + wm * 32 + fm * 16 + (l >> 4) * 4;
      int gcol = col0 + wn * 32 + fn * 16 + (l & 15);
      u16x4 bt;
#pragma unroll
      for (int r = 0; r < 4; ++r) {
        float v = acc[fm][fn][r];
        C[(size_t)(grow0 + r) * 256 + gcol] = v;
        bt[r] = f2bf(v);
      }
      *(u16x4*)(bt1 + (size_t)gcol * 8192 + grow0) = bt;
    }
  }
}

// ---------------- e1/e2 vectors (layer 1): wave per row ----------------
__global__ __launch_bounds__(256) void calc_e_k(
    const float* __restrict__ Wh, const float* __restrict__ a,
    float* __restrict__ e1, float* __restrict__ e2, int F)
{
  int row = blockIdx.x * 4 + (threadIdx.x >> 6);
  int l = threadIdx.x & 63;
  const float* r = Wh + (size_t)row * F;
  float s1 = 0.f, s2 = 0.f;
  for (int f = l; f < F; f += 64) {
    float v = r[f];
    s1 += v * a[f];
    s2 += v * a[F + f];
  }
#pragma unroll
  for (int off = 32; off; off >>= 1) {
    s1 += __shfl_down(s1, off);
    s2 += __shfl_down(s2, off);
  }
  if (l == 0) { e1[row] = s1; e2[row] = s2; }
}

// ---------------- layer-1 masked softmax + inline adj bit-pack + bf16 dual write ----------------
// att1 (fp32) is write-only downstream (gemm consumes att1b) -> nontemporal
// stores (via ext-vector f32x4, which the builtin accepts) keep att1b resident
// in the 256MB LLC for gemm_bfA's re-read.
__global__ __launch_bounds__(256) void att_softmax1_k(
    const int* __restrict__ adj, const float* __restrict__ e1,
    const float* __restrict__ e2, float* __restrict__ att,
    unsigned short* __restrict__ attb, unsigned* __restrict__ bits)
{
  __shared__ float red[4];
  int i = blockIdx.x, t = threadIdx.x;
  const int4* arow = (const int4*)(adj + (size_t)i * 8192);
  unsigned* brow = bits + (size_t)i * 256;
  float e1i = e1[i];
  float4 vv[8];
  float s = 0.f;
#pragma unroll
  for (int it = 0; it < 8; ++it) {
    int j4 = t + it * 256;               // int4/float4 index
    int4 a4 = arow[j4];
    float4 ev = *(const float4*)(e2 + j4 * 4);
    unsigned n = (unsigned)(a4.x > 0) | ((unsigned)(a4.y > 0) << 1)
               | ((unsigned)(a4.z > 0) << 2) | ((unsigned)(a4.w > 0) << 3);
    unsigned v = n << ((t & 7) * 4);
    v |= __shfl_xor(v, 1);
    v |= __shfl_xor(v, 2);
    v |= __shfl_xor(v, 4);
    if ((t & 7) == 0) brow[it * 32 + (t >> 3)] = v;
    float e, p0, p1, p2, p3;
    e = e1i + ev.x; e = e > 0.f ? e : LRELU_ALPHA * e; p0 = (a4.x > 0) ? __expf(e) : 0.f;
    e = e1i + ev.y; e = e > 0.f ? e : LRELU_ALPHA * e; p1 = (a4.y > 0) ? __expf(e) : 0.f;
    e = e1i + ev.z; e = e > 0.f ? e : LRELU_ALPHA * e; p2 = (a4.z > 0) ? __expf(e) : 0.f;
    e = e1i + ev.w; e = e > 0.f ? e : LRELU_ALPHA * e; p3 = (a4.w > 0) ? __expf(e) : 0.f;
    vv[it] = make_float4(p0, p1, p2, p3);
    s += (p0 + p1) + (p2 + p3);
  }
#pragma unroll
  for (int off = 32; off; off >>= 1) s += __shfl_xor(s, off);
  if ((t & 63) == 0) red[t >> 6] = s;
  __syncthreads();
  s = red[0] + red[1] + red[2] + red[3];
  float inv = 1.f / s;
  f32x4* orow = (f32x4*)(att + (size_t)i * 8192);
  unsigned short* obrow = attb + (size_t)i * 8192;
#pragma unroll
  for (int it = 0; it < 8; ++it) {
    int j4 = t + it * 256;
    float4 p = vv[it];
    f32x4 pv;
    pv[0] = p.x * inv; pv[1] = p.y * inv; pv[2] = p.z * inv; pv[3] = p.w * inv;
    __builtin_nontemporal_store(pv, &orow[j4]);   // dead store downstream: bypass LLC
    u16x4 b;
    b[0] = f2bf(pv[0]); b[1] = f2bf(pv[1]); b[2] = f2bf(pv[2]); b[3] = f2bf(pv[3]);
    *(u16x4*)(obrow + j4 * 4) = b;
  }
}

// ---------------- layer-2 masked softmax (bits mask), fp32 out only ----------------
__global__ __launch_bounds__(256) void att_softmax2_k(
    const unsigned* __restrict__ bits, const float* __restrict__ e1,
    const float* __restrict__ e2, float* __restrict__ att)
{
  __shared__ unsigned bw[256];
  __shared__ float red[4];
  int i = blockIdx.x, t = threadIdx.x;
  bw[t] = bits[(size_t)i * 256 + t];
  float e1i = e1[i];
  __syncthreads();
  float4 vv[8];
  float s = 0.f;
#pragma unroll
  for (int it = 0; it < 8; ++it) {
    int j4 = t + it * 256;
    float4 ev = *(const float4*)(e2 + j4 * 4);
    unsigned wb = bw[j4 >> 3];
    int b0 = (j4 & 7) * 4;
    float e, p0, p1, p2, p3;
    e = e1i + ev.x; e = e > 0.f ? e : LRELU_ALPHA * e; p0 = ((wb >> (b0 + 0)) & 1) ? __expf(e) : 0.f;
    e = e1i + ev.y; e = e > 0.f ? e : LRELU_ALPHA * e; p1 = ((wb >> (b0 + 1)) & 1) ? __expf(e) : 0.f;
    e = e1i + ev.z; e = e > 0.f ? e : LRELU_ALPHA * e; p2 = ((wb >> (b0 + 2)) & 1) ? __expf(e) : 0.f;
    e = e1i + ev.w; e = e > 0.f ? e : LRELU_ALPHA * e; p3 = ((wb >> (b0 + 3)) & 1) ? __expf(e) : 0.f;
    vv[it] = make_float4(p0, p1, p2, p3);
    s += (p0 + p1) + (p2 + p3);
  }
#pragma unroll
  for (int off = 32; off; off >>= 1) s += __shfl_xor(s, off);
  if ((t & 63) == 0) red[t >> 6] = s;
  __syncthreads();
  s = red[0] + red[1] + red[2] + red[3];
  float inv = 1.f / s;
  float4* orow = (float4*)(att + (size_t)i * 8192);
#pragma unroll
  for (int it = 0; it < 8; ++it) {
    float4 p = vv[it];
    p.x *= inv; p.y *= inv; p.z *= inv; p.w *= inv;
    orow[t + it * 256] = p;
  }
}

// ---------------- MFMA bf16 GEMM (bf16 A, layer 1): part[z] = att1b @ bt1^T ----------------
__global__ __launch_bounds__(256) void gemm_bfA_k(
    const unsigned short* __restrict__ A,    // att1b [8192][8192] bf16
    const unsigned short* __restrict__ BT,   // bt1 [256][8192] bf16
    float* __restrict__ part)                // [4][8192][256]
{
  constexpr int BM = 64, BN = 64, BK = 64;
  __shared__ __align__(16) unsigned short As[BM * 64];   // row stride 128 B
  __shared__ __align__(16) unsigned short Bs[BN * 64];
  int t = threadIdx.x;
  int row0 = blockIdx.x * BM;
  int col0 = blockIdx.y * BN;
  int z = blockIdx.z;
  int kt0 = z * 32;
  int w = t >> 6, l = t & 63;
  int wm = w >> 1, wn = w & 1;

  f32x4 acc[2][2] = {};

  int ra0 = 16 * w + (l >> 3);
  int ra1 = ra0 + 8;
  int sseg = ((l & 7) ^ (ra0 & 7)) * 8;      // (ra1&7)==(ra0&7)
  const unsigned short* gA0 = A + (size_t)(row0 + ra0) * 8192 + kt0 * BK + sseg;
  const unsigned short* gA1 = A + (size_t)(row0 + ra1) * 8192 + kt0 * BK + sseg;
  const unsigned short* gB0 = BT + (size_t)(col0 + ra0) * 8192 + kt0 * BK + sseg;
  const unsigned short* gB1 = BT + (size_t)(col0 + ra1) * 8192 + kt0 * BK + sseg;
  unsigned short* lA0 = As + (16 * w) * 64;        // wave-uniform chunk bases
  unsigned short* lA1 = As + (16 * w + 8) * 64;
  unsigned short* lB0 = Bs + (16 * w) * 64;
  unsigned short* lB1 = Bs + (16 * w + 8) * 64;

  for (int kt = 0; kt < 32; ++kt) {
    __syncthreads();
    gload16(gA0 + kt * BK, lA0);
    gload16(gA1 + kt * BK, lA1);
    gload16(gB0 + kt * BK, lB0);
    gload16(gB1 + kt * BK, lB1);
    __syncthreads();   // compiler drains vmcnt before barrier -> LDS valid
#pragma unroll
    for (int kk = 0; kk < BK; kk += 32) {
      bf16x8 af[2], bfr[2];
      int kb = (kk + (l >> 4) * 8) * 2;
#pragma unroll
      for (int fm = 0; fm < 2; ++fm) {
        int r = wm * 32 + fm * 16 + (l & 15);
        af[fm] = *(const bf16x8*)((const char*)As + ((r * 128 + kb) ^ ((r & 7) << 4)));
      }
#pragma unroll
      for (int fn = 0; fn < 2; ++fn) {
        int c = wn * 32 + fn * 16 + (l & 15);
        bfr[fn] = *(const bf16x8*)((const char*)Bs + ((c * 128 + kb) ^ ((c & 7) << 4)));
      }
#pragma unroll
      for (int fm = 0; fm < 2; ++fm)
#pragma unroll
        for (int fn = 0; fn < 2; ++fn)
          acc[fm][fn] = __builtin_amdgcn_mfma_f32_16x16x32_bf16(af[fm], bfr[fn], acc[fm][fn], 0, 0, 0);
    }
  }
#pragma unroll
  for (int fm = 0; fm < 2; ++fm) {
#pragma unroll
    for (int fn = 0; fn < 2; ++fn) {
#pragma unroll
      for (int r = 0; r < 4; ++r) {
        int grow = row0 + wm * 32 + fm * 16 + (l >> 4) * 4 + r;
        int gcol = col0 + wn * 32 + fn * 16 + (l & 15);
        part[((size_t)z * 8192 + grow) * 256 + gcol] = acc[fm][fn][r];
      }
    }
  }
}

// ---------------- fused layer boundary: part1 -> h1 (ELU) -> wh2 -> bt2 + e1b/e2b ----------------
__global__ __launch_bounds__(256) void epilogue2_k(
    const float* __restrict__ part, const float* __restrict__ W2,
    const float* __restrict__ a2, float* __restrict__ h1,
    unsigned short* __restrict__ bt2, float* __restrict__ e1b,
    float* __restrict__ e2b)
{
  __shared__ float w2s[256][17];
  __shared__ float h1s[4096];
  int t = threadIdx.x;
  int row0 = blockIdx.x * 16;
  { // load W2 [256][16]
    const float4* src = (const float4*)(W2 + t * 16);
    float4 v0 = src[0], v1 = src[1], v2 = src[2], v3 = src[3];
    float* d = &w2s[t][0];
    d[0]=v0.x; d[1]=v0.y; d[2]=v0.z; d[3]=v0.w;
    d[4]=v1.x; d[5]=v1.y; d[6]=v1.z; d[7]=v1.w;
    d[8]=v2.x; d[9]=v2.y; d[10]=v2.z; d[11]=v2.w;
    d[12]=v3.x; d[13]=v3.y; d[14]=v3.z; d[15]=v3.w;
  }
  size_t base = (size_t)row0 * 256;
#pragma unroll
  for (int it = 0; it < 16; ++it) {
    int e = t + it * 256;
    float s = (part[base + e] + part[2097152 + base + e])
            + (part[2 * 2097152 + base + e] + part[3 * 2097152 + base + e]);
    float h = s > 0.f ? s : expm1f(s);
    h1[base + e] = h;
    h1s[e] = h;
  }
  __syncthreads();
  int r = t >> 4, c = t & 15;
  const float* hrow = &h1s[r * 256];
  float acc = 0.f;
#pragma unroll 8
  for (int k = 0; k < 256; ++k)
    acc = fmaf(hrow[k], w2s[k][c], acc);
  bt2[(size_t)c * 8192 + row0 + r] = f2bf(acc);
  float v1 = acc * a2[c];
  float v2 = acc * a2[16 + c];
#pragma unroll
  for (int off = 8; off; off >>= 1) {
    v1 += __shfl_xor(v1, off);
    v2 += __shfl_xor(v2, off);
  }
  if (c == 0) { e1b[row0 + r] = v1; e2b[row0 + r] = v2; }
}

// ---------------- MFMA bf16 GEMM (layer 2, fp32 A): part2[z] = att2 @ bt2^T ----------------
__global__ __launch_bounds__(256) void gemm_mfma2_k(
    const float* __restrict__ A, const unsigned short* __restrict__ BT,
    float* __restrict__ part)
{
  constexpr int BM = 64, BN = 16, BK = 64;
  __shared__ __align__(16) char As[BM * 128];
  __shared__ __align__(16) char Bs[BN * 128];
  int t = threadIdx.x;
  int row0 = blockIdx.x * BM;
  int z = blockIdx.z;
  int kt0 = z * 32, kt1 = kt0 + 32;
  int w = t >> 6, l = t & 63;

  f32x4 acc = {};

  int ar = t >> 2, aseg = t & 3;
  int swzA = (ar & 7) << 4;

  for (int kt = kt0; kt < kt1; ++kt) {
    __syncthreads();
    {
      const float4* src = (const float4*)(A + (size_t)(row0 + ar) * 8192 + kt * BK + aseg * 16);
      float4 v0 = src[0], v1 = src[1], v2 = src[2], v3 = src[3];
      u16x8 c0, c1;
      c0[0]=f2bf(v0.x); c0[1]=f2bf(v0.y); c0[2]=f2bf(v0.z); c0[3]=f2bf(v0.w);
      c0[4]=f2bf(v1.x); c0[5]=f2bf(v1.y); c0[6]=f2bf(v1.z); c0[7]=f2bf(v1.w);
      c1[0]=f2bf(v2.x); c1[1]=f2bf(v2.y); c1[2]=f2bf(v2.z); c1[3]=f2bf(v2.w);
      c1[4]=f2bf(v3.x); c1[5]=f2bf(v3.y); c1[6]=f2bf(v3.z); c1[7]=f2bf(v3.w);
      int base = ar * 128 + aseg * 32;
      *(u16x8*)(As + ((base) ^ swzA)) = c0;
      *(u16x8*)(As + ((base + 16) ^ swzA)) = c1;
    }
    {
      int br = t >> 4, seg = t & 15;
      const u16x4* src = (const u16x4*)(BT + (size_t)br * 8192 + kt * BK + seg * 4);
      u16x4 b0 = src[0];
      int base = br * 128 + seg * 8;
      int swz = (br & 7) << 4;
      *(u16x4*)(Bs + (base ^ swz)) = b0;
    }
    __syncthreads();
#pragma unroll
    for (int kk = 0; kk < BK; kk += 32) {
      int kb = (kk + (l >> 4) * 8) * 2;
      int r = w * 16 + (l & 15);
      bf16x8 af = *(const bf16x8*)(As + ((r * 128 + kb) ^ ((r & 7) << 4)));
      int c = l & 15;
      bf16x8 bf = *(const bf16x8*)(Bs + ((c * 128 + kb) ^ ((c & 7) << 4)));
      acc = __builtin_amdgcn_mfma_f32_16x16x32_bf16(af, bf, acc, 0, 0, 0);
    }
  }
#pragma unroll
  for (int r = 0; r < 4; ++r) {
    int grow = row0 + w * 16 + (l >> 4) * 4 + r;
    int gcol = l & 15;
    part[((size_t)z * 8192 + grow) * 16 + gcol] = acc[r];
  }
}

// ---------------- split-K reduce + sigmoid (4 partials) ----------------
__global__ void reduce_sig_k(const float* __restrict__ part, float* __restrict__ out, int total)
{
  int i = blockIdx.x * 256 + threadIdx.x;
  if (i < total) {
    float s = part[i] + part[total + i] + part[2 * (size_t)total + i] + part[3 * (size_t)total + i];
    out[i] = 1.f / (1.f + __expf(-s));
  }
}

extern "C" void kernel_launch(void* const* d_in, const int* in_sizes, int n_in,
                              void* d_out, int out_size, void* d_ws, size_t ws_size,
                              hipStream_t stream)
{
  const float* x   = (const float*)d_in[0];
  const int*   adj = (const int*)d_in[1];
  const float* W1  = (const float*)d_in[2];
  const float* a1  = (const float*)d_in[3];
  const float* W2  = (const float*)d_in[4];
  const float* a2  = (const float*)d_in[5];

  float* out  = (float*)d_out;                 // [8192*16]
  float* h1   = out + 131072;                  // [8192*256]
  float* att1 = h1 + 2097152;                  // [8192*8192]
  float* att2 = att1 + 67108864;               // [8192*8192]

  float* ws = (float*)d_ws;
  float* wh1 = ws;                                            // 2097152 f
  unsigned short* bt1 = (unsigned short*)(wh1 + 2097152);     // 2097152 u16
  float* e1a = wh1 + 2097152 + 1048576;
  float* e2a = e1a + 8192;
  unsigned short* bt2 = (unsigned short*)(e2a + 8192);        // 131072 u16
  float* e1b = (float*)(bt2 + 131072);
  float* e2b = e1b + 8192;
  float* part2 = e2b + 8192;                                  // 4*131072 f
  unsigned* bits = (unsigned*)(part2 + 524288);               // 2097152 u32
  float* part1 = (float*)(bits + 2097152);                    // 4*2097152 f
  unsigned short* att1b = (unsigned short*)(part1 + 8388608); // 67108864 u16
  unsigned short* w1t = att1b + 67108864;                     // 131072 u16

  // ---- layer 1 ----
  transpose_bf16_k<<<dim3(8, 16), dim3(32, 8), 0, stream>>>(W1, w1t, 512, 256);
  gemm_wh1_k<<<dim3(128, 4), 256, 0, stream>>>(x, w1t, wh1, bt1);
  calc_e_k<<<2048, 256, 0, stream>>>(wh1, a1, e1a, e2a, 256);
  att_softmax1_k<<<8192, 256, 0, stream>>>(adj, e1a, e2a, att1, att1b, bits);
  gemm_bfA_k<<<dim3(128, 4, 4), 256, 0, stream>>>(att1b, bt1, part1);

  // ---- layer boundary (fused): h1, bt2, e1b/e2b ----
  epilogue2_k<<<512, 256, 0, stream>>>(part1, W2, a2, h1, bt2, e1b, e2b);

  // ---- layer 2 ----
  att_softmax2_k<<<8192, 256, 0, stream>>>(bits, e1b, e2b, att2);
  gemm_mfma2_k<<<dim3(128, 1, 4), 256, 0, stream>>>(att2, bt2, part2);
  reduce_sig_k<<<512, 256, 0, stream>>>(part2, out, 131072);
}